// Round 1
// baseline (502.188 us; speedup 1.0000x reference)
//
#include <hip/hip_runtime.h>
#include <stdint.h>

typedef unsigned short u16;
typedef __attribute__((ext_vector_type(8))) unsigned short u16x8;
typedef __attribute__((ext_vector_type(8))) __bf16 bf16x8;
typedef __attribute__((ext_vector_type(4))) float f32x4;
typedef __attribute__((ext_vector_type(8))) float f32x8;

#define AS_G __attribute__((address_space(1)))
#define AS_L __attribute__((address_space(3)))

static __device__ __forceinline__ void gload_lds16(const u16* g, u16* l) {
  __builtin_amdgcn_global_load_lds((AS_G void*)(u16*)g, (AS_L void*)l, 16, 0, 0);
}

static __device__ __forceinline__ u16 f2bf(float f) {
  union { float f; unsigned u; } v; v.f = f;
  return (u16)((v.u + 0x7FFFu + ((v.u >> 16) & 1u)) >> 16);
}
static __device__ __forceinline__ float bf2f(u16 b) {
  union { unsigned u; float f; } v; v.u = ((unsigned)b) << 16;
  return v.f;
}

// ---------------------------------------------------------------- cast fp32->bf16
__global__ __launch_bounds__(256) void cast_all(
    const float* __restrict__ x, const float* __restrict__ Wq,
    const float* __restrict__ Wk, const float* __restrict__ Wv,
    const float* __restrict__ Wo,
    u16* __restrict__ xb, u16* __restrict__ Wcat, u16* __restrict__ Wob)
{
  const int NX = (4096 * 2048) / 8;
  const int NW = (2048 * 2048) / 8;
  const int total = NX + 4 * NW;
  for (int i = blockIdx.x * 256 + threadIdx.x; i < total; i += gridDim.x * 256) {
    const float* src; u16* dst; int idx;
    if (i < NX)               { src = x;  dst = xb;                 idx = i; }
    else if (i < NX + NW)     { src = Wq; dst = Wcat;               idx = i - NX; }
    else if (i < NX + 2*NW)   { src = Wk; dst = Wcat + 2048*2048;   idx = i - NX - NW; }
    else if (i < NX + 3*NW)   { src = Wv; dst = Wcat + 2*2048*2048; idx = i - NX - 2*NW; }
    else                      { src = Wo; dst = Wob;                idx = i - NX - 3*NW; }
    f32x8 v = *(const f32x8*)(src + (size_t)idx * 8);
    u16x8 o;
    #pragma unroll
    for (int e = 0; e < 8; e++) o[e] = f2bf(v[e]);
    *(u16x8*)(dst + (size_t)idx * 8) = o;
  }
}

// ---------------------------------------------------------------- NT GEMM (m97 structure)
// C[i][j] = sum_k A[i][k]*B[j][k]; A [M][K] bf16, B [N][K] bf16.
// 128x128 tile, BK=32, 4 waves each 64x64, global_load_lds width 16.
template<bool FP32OUT>
__global__ __launch_bounds__(256) void gemm_nt(
    const u16* __restrict__ A, const u16* __restrict__ B,
    void* __restrict__ Cout, const float* __restrict__ bias,
    int M, int N, int K)
{
  __shared__ u16 As[128 * 32];
  __shared__ u16 Bs[128 * 32];
  const int tid = threadIdx.x;
  const int lane = tid & 63;
  const int wid = tid >> 6;
  const int wr = wid >> 1, wc = wid & 1;
  const int row0 = blockIdx.y * 128, col0 = blockIdx.x * 128;

  const u16* Ag = A + (size_t)(row0 + (tid >> 2)) * K + (tid & 3) * 8;
  const u16* Bg = B + (size_t)(col0 + (tid >> 2)) * K + (tid & 3) * 8;
  u16* AsW0 = As + wid * 512;
  u16* AsW1 = As + 2048 + wid * 512;
  u16* BsW0 = Bs + wid * 512;
  u16* BsW1 = Bs + 2048 + wid * 512;

  f32x4 acc[4][4] = {};

  for (int k0 = 0; k0 < K; k0 += 32) {
    gload_lds16(Ag + k0, AsW0);
    gload_lds16(Ag + (size_t)64 * K + k0, AsW1);
    gload_lds16(Bg + k0, BsW0);
    gload_lds16(Bg + (size_t)64 * K + k0, BsW1);
    __syncthreads();
    bf16x8 a[4], b[4];
    #pragma unroll
    for (int mt = 0; mt < 4; mt++)
      a[mt] = *(const bf16x8*)(As + (wr*64 + mt*16 + (lane & 15)) * 32 + (lane >> 4) * 8);
    #pragma unroll
    for (int nt = 0; nt < 4; nt++)
      b[nt] = *(const bf16x8*)(Bs + (wc*64 + nt*16 + (lane & 15)) * 32 + (lane >> 4) * 8);
    #pragma unroll
    for (int mt = 0; mt < 4; mt++)
      #pragma unroll
      for (int nt = 0; nt < 4; nt++)
        acc[mt][nt] = __builtin_amdgcn_mfma_f32_16x16x32_bf16(a[mt], b[nt], acc[mt][nt], 0, 0, 0);
    __syncthreads();
  }

  #pragma unroll
  for (int mt = 0; mt < 4; mt++) {
    #pragma unroll
    for (int nt = 0; nt < 4; nt++) {
      #pragma unroll
      for (int e = 0; e < 4; e++) {
        int r = row0 + wr*64 + mt*16 + (lane >> 4) * 4 + e;
        int c = col0 + wc*64 + nt*16 + (lane & 15);
        if constexpr (FP32OUT) {
          ((float*)Cout)[(size_t)r * N + c] = acc[mt][nt][e] + bias[c];
        } else {
          ((u16*)Cout)[(size_t)r * N + c] = f2bf(acc[mt][nt][e]);
        }
      }
    }
  }
}

// ---------------------------------------------------------------- per-head LayerNorm on Q,K (in place)
// QKV [4096][6144]; heads of 128; fp32 stats, bf16 out. eps=1e-5.
__global__ __launch_bounds__(256) void ln_qk(u16* __restrict__ QKV)
{
  const int row = blockIdx.x;        // 0..4095 (b*2048+l)
  const int t = threadIdx.x;
  const int h = t >> 4;              // 16 threads per head
  const int e0 = (t & 15) * 8;
  u16* rowp = QKV + (size_t)row * 6144;
  #pragma unroll
  for (int part = 0; part < 2; part++) {   // 0: Q, 1: K
    u16* p = rowp + part * 2048 + h * 128 + e0;
    u16x8 raw = *(const u16x8*)p;
    float v[8]; float s = 0.f, s2 = 0.f;
    #pragma unroll
    for (int e = 0; e < 8; e++) { v[e] = bf2f(raw[e]); s += v[e]; s2 += v[e]*v[e]; }
    #pragma unroll
    for (int m = 1; m < 16; m <<= 1) { s += __shfl_xor(s, m); s2 += __shfl_xor(s2, m); }
    float mu = s * (1.f / 128.f);
    float var = s2 * (1.f / 128.f) - mu * mu;
    float rstd = rsqrtf(var + 1e-5f);
    u16x8 o;
    #pragma unroll
    for (int e = 0; e < 8; e++) o[e] = f2bf((v[e] - mu) * rstd);
    *(u16x8*)p = o;
  }
}

// ---------------------------------------------------------------- V -> Vt [b,h,d,l]
__global__ __launch_bounds__(256) void transpose_v(const u16* __restrict__ QKV, u16* __restrict__ Vt)
{
  __shared__ u16 T[64 * 65];
  const int d0 = blockIdx.x * 64;    // 0 or 64
  const int l0 = blockIdx.y * 64;    // seq tile
  const int bh = blockIdx.z;         // b*16+h
  const int b = bh >> 4, h = bh & 15;
  const int t = threadIdx.x;
  #pragma unroll
  for (int i = 0; i < 2; i++) {
    int c = t + i * 256;
    int l = c >> 3, dc = (c & 7) * 8;
    u16x8 v = *(const u16x8*)(QKV + (size_t)(b*2048 + l0 + l) * 6144 + 4096 + h*128 + d0 + dc);
    #pragma unroll
    for (int e = 0; e < 8; e++) T[l * 65 + dc + e] = v[e];
  }
  __syncthreads();
  #pragma unroll
  for (int i = 0; i < 2; i++) {
    int c = t + i * 256;
    int d = c >> 3, lc = (c & 7) * 8;
    u16x8 o;
    #pragma unroll
    for (int e = 0; e < 8; e++) o[e] = T[(lc + e) * 65 + d];
    *(u16x8*)(Vt + (size_t)((b*16 + h) * 128 + d0 + d) * 2048 + l0 + lc) = o;
  }
}

// ---------------------------------------------------------------- causal flash attention
// 4 waves; wave w owns q-rows [w*16, w*16+16). QBLK=KVBLK=64. hd=128.
// LDS tiles XOR-swizzled: byte ^= (row&7)<<4 to kill the [*][128]-row bank conflict.
__global__ __launch_bounds__(256) void attn(
    const u16* __restrict__ QKV, const u16* __restrict__ Vt, u16* __restrict__ AO)
{
  const int qt = blockIdx.x;     // 0..31
  const int h  = blockIdx.y;     // 0..15
  const int b  = blockIdx.z;     // 0..1
  const int l0 = qt * 64;
  const int tid = threadIdx.x, lane = tid & 63, wid = tid >> 6;

  __shared__ u16 Qs[64 * 128];
  __shared__ u16 Ks[64 * 128];
  __shared__ u16 Vs[128 * 64];
  __shared__ u16 Ps[4][16 * 64];

  // stage Q once (swizzled)
  #pragma unroll
  for (int i = 0; i < 4; i++) {
    int c = tid + i * 256;
    int r = c >> 4, cb = (c & 15) * 16;
    u16x8 v = *(const u16x8*)(QKV + (size_t)(b*2048 + l0 + r) * 6144 + h*128 + (cb >> 1));
    *(u16x8*)((char*)Qs + r * 256 + (cb ^ ((r & 7) << 4))) = v;
  }
  __syncthreads();

  bf16x8 qa[4];
  #pragma unroll
  for (int ks = 0; ks < 4; ks++) {
    int r = wid * 16 + (lane & 15);
    int cb = ks * 64 + (lane >> 4) * 16;
    qa[ks] = *(const bf16x8*)((const char*)Qs + r * 256 + (cb ^ ((lane & 7) << 4)));
  }

  f32x4 o[8] = {};
  float mrun[4] = {-1e30f, -1e30f, -1e30f, -1e30f};
  float lrun[4] = {};
  const float SC = 0.08838834764831845f * 1.4426950408889634f;  // 1/sqrt(128) * log2(e)

  for (int t = 0; t <= qt; t++) {
    const int j0 = t * 64;
    #pragma unroll
    for (int i = 0; i < 4; i++) {          // stage K tile
      int c = tid + i * 256;
      int r = c >> 4, cb = (c & 15) * 16;
      u16x8 v = *(const u16x8*)(QKV + (size_t)(b*2048 + j0 + r) * 6144 + 2048 + h*128 + (cb >> 1));
      *(u16x8*)((char*)Ks + r * 256 + (cb ^ ((r & 7) << 4))) = v;
    }
    #pragma unroll
    for (int i = 0; i < 4; i++) {          // stage V^T tile
      int c = tid + i * 256;
      int r = c >> 3, cb = (c & 7) * 16;   // r = d, cb = j-byte
      u16x8 v = *(const u16x8*)(Vt + (size_t)((b*16 + h) * 128 + r) * 2048 + j0 + (cb >> 1));
      *(u16x8*)((char*)Vs + r * 128 + (cb ^ ((r & 7) << 4))) = v;
    }
    __syncthreads();

    // S = Q K^T (per wave 16x64)
    f32x4 s[4] = {};
    #pragma unroll
    for (int nt = 0; nt < 4; nt++) {
      #pragma unroll
      for (int ks = 0; ks < 4; ks++) {
        int r = nt * 16 + (lane & 15);
        int cb = ks * 64 + (lane >> 4) * 16;
        bf16x8 kb = *(const bf16x8*)((const char*)Ks + r * 256 + (cb ^ ((lane & 7) << 4)));
        s[nt] = __builtin_amdgcn_mfma_f32_16x16x32_bf16(qa[ks], kb, s[nt], 0, 0, 0);
      }
    }

    const bool diag = (t == qt);
    #pragma unroll
    for (int nt = 0; nt < 4; nt++) {
      #pragma unroll
      for (int e = 0; e < 4; e++) {
        float v = s[nt][e] * SC;
        if (diag) {
          int i_loc = wid * 16 + (lane >> 4) * 4 + e;
          int j_loc = nt * 16 + (lane & 15);
          if (j_loc > i_loc) v = -1e30f;
        }
        s[nt][e] = v;
      }
    }

    // online softmax (rows live on 16-lane groups)
    float alpha[4];
    #pragma unroll
    for (int e = 0; e < 4; e++) {
      float v = fmaxf(fmaxf(s[0][e], s[1][e]), fmaxf(s[2][e], s[3][e]));
      v = fmaxf(v, __shfl_xor(v, 1));
      v = fmaxf(v, __shfl_xor(v, 2));
      v = fmaxf(v, __shfl_xor(v, 4));
      v = fmaxf(v, __shfl_xor(v, 8));
      float mi = fmaxf(mrun[e], v);
      alpha[e] = exp2f(mrun[e] - mi);
      mrun[e] = mi;
    }
    float rs[4] = {};
    #pragma unroll
    for (int nt = 0; nt < 4; nt++)
      #pragma unroll
      for (int e = 0; e < 4; e++) {
        float p = exp2f(s[nt][e] - mrun[e]);
        s[nt][e] = p;
        rs[e] += p;
      }
    #pragma unroll
    for (int e = 0; e < 4; e++) {
      rs[e] += __shfl_xor(rs[e], 1);
      rs[e] += __shfl_xor(rs[e], 2);
      rs[e] += __shfl_xor(rs[e], 4);
      rs[e] += __shfl_xor(rs[e], 8);
      lrun[e] = lrun[e] * alpha[e] + rs[e];
    }
    #pragma unroll
    for (int dt = 0; dt < 8; dt++)
      #pragma unroll
      for (int e = 0; e < 4; e++)
        o[dt][e] *= alpha[e];

    // P -> per-wave LDS (swizzled) for PV A-operand redistribution
    char* PsW = (char*)Ps[wid];
    #pragma unroll
    for (int nt = 0; nt < 4; nt++)
      #pragma unroll
      for (int e = 0; e < 4; e++) {
        int i_ = (lane >> 4) * 4 + e;
        int jb = (nt * 16 + (lane & 15)) * 2;
        *(u16*)(PsW + i_ * 128 + (jb ^ ((i_ & 7) << 4))) = f2bf(s[nt][e]);
      }

    // O += P V
    #pragma unroll
    for (int ks = 0; ks < 2; ks++) {
      int ir = lane & 15;
      int jb = ks * 64 + (lane >> 4) * 16;
      bf16x8 pa = *(const bf16x8*)(PsW + ir * 128 + (jb ^ ((ir & 7) << 4)));
      #pragma unroll
      for (int dt = 0; dt < 8; dt++) {
        int dr = dt * 16 + (lane & 15);
        bf16x8 vb = *(const bf16x8*)((const char*)Vs + dr * 128 + (jb ^ ((lane & 7) << 4)));
        o[dt] = __builtin_amdgcn_mfma_f32_16x16x32_bf16(pa, vb, o[dt], 0, 0, 0);
      }
    }
    __syncthreads();
  }

  #pragma unroll
  for (int e = 0; e < 4; e++) {
    float inv = 1.0f / lrun[e];
    int rglob = b * 2048 + l0 + wid * 16 + (lane >> 4) * 4 + e;
    #pragma unroll
    for (int dt = 0; dt < 8; dt++)
      AO[(size_t)rglob * 2048 + h * 128 + dt * 16 + (lane & 15)] = f2bf(o[dt][e] * inv);
  }
}

// ---------------------------------------------------------------- launch
extern "C" void kernel_launch(void* const* d_in, const int* in_sizes, int n_in,
                              void* d_out, int out_size, void* d_ws, size_t ws_size,
                              hipStream_t stream)
{
  const float* x  = (const float*)d_in[0];
  const float* Wq = (const float*)d_in[1];
  const float* Wk = (const float*)d_in[2];
  const float* Wv = (const float*)d_in[3];
  const float* Wo = (const float*)d_in[4];
  const float* bo = (const float*)d_in[5];

  char* ws = (char*)d_ws;
  // layout (bytes):   [xb / AO 16 MB][Wcat / Vt 24 MB][Wob 8 MB][QKV 48 MB] = 96 MB
  u16* xb   = (u16*)(ws);
  u16* Wcat = (u16*)(ws + 16777216);
  u16* Wob  = (u16*)(ws + 16777216 + 25165824);
  u16* QKV  = (u16*)(ws + 16777216 + 25165824 + 8388608);
  u16* AO   = xb;    // reuse: xb dead after gemm_qkv
  u16* Vt   = Wcat;  // reuse: Wcat dead after gemm_qkv

  cast_all<<<dim3(2048), dim3(256), 0, stream>>>(x, Wq, Wk, Wv, Wo, xb, Wcat, Wob);
  gemm_nt<false><<<dim3(48, 32), dim3(256), 0, stream>>>(xb, Wcat, (void*)QKV, nullptr, 4096, 6144, 2048);
  ln_qk<<<dim3(4096), dim3(256), 0, stream>>>(QKV);
  transpose_v<<<dim3(2, 32, 32), dim3(256), 0, stream>>>(QKV, Vt);
  attn<<<dim3(32, 16, 2), dim3(256), 0, stream>>>(QKV, Vt, AO);
  gemm_nt<true><<<dim3(16, 32), dim3(256), 0, stream>>>(AO, Wob, d_out, bo, 4096, 2048, 2048);
}

// Round 2
// 333.669 us; speedup vs baseline: 1.5050x; 1.5050x over previous
//
#include <hip/hip_runtime.h>
#include <stdint.h>

typedef unsigned short u16;
typedef __attribute__((ext_vector_type(8))) unsigned short u16x8;
typedef __attribute__((ext_vector_type(8))) __bf16 bf16x8;
typedef __attribute__((ext_vector_type(4))) float f32x4;
typedef __attribute__((ext_vector_type(8))) float f32x8;

#define AS_G __attribute__((address_space(1)))
#define AS_L __attribute__((address_space(3)))

static __device__ __forceinline__ void gload_lds16(const u16* g, u16* l) {
  __builtin_amdgcn_global_load_lds((AS_G void*)(u16*)g, (AS_L void*)l, 16, 0, 0);
}

static __device__ __forceinline__ u16 f2bf(float f) {
  union { float f; unsigned u; } v; v.f = f;
  return (u16)((v.u + 0x7FFFu + ((v.u >> 16) & 1u)) >> 16);
}
static __device__ __forceinline__ float bf2f(u16 b) {
  union { unsigned u; float f; } v; v.u = ((unsigned)b) << 16;
  return v.f;
}

// ---------------------------------------------------------------- cast fp32->bf16
__global__ __launch_bounds__(256) void cast_all(
    const float* __restrict__ x, const float* __restrict__ Wq,
    const float* __restrict__ Wk, const float* __restrict__ Wv,
    const float* __restrict__ Wo,
    u16* __restrict__ xb, u16* __restrict__ Wcat, u16* __restrict__ Wob)
{
  const int NX = (4096 * 2048) / 8;
  const int NW = (2048 * 2048) / 8;
  const int total = NX + 4 * NW;
  for (int i = blockIdx.x * 256 + threadIdx.x; i < total; i += gridDim.x * 256) {
    const float* src; u16* dst; int idx;
    if (i < NX)               { src = x;  dst = xb;                 idx = i; }
    else if (i < NX + NW)     { src = Wq; dst = Wcat;               idx = i - NX; }
    else if (i < NX + 2*NW)   { src = Wk; dst = Wcat + 2048*2048;   idx = i - NX - NW; }
    else if (i < NX + 3*NW)   { src = Wv; dst = Wcat + 2*2048*2048; idx = i - NX - 2*NW; }
    else                      { src = Wo; dst = Wob;                idx = i - NX - 3*NW; }
    f32x8 v = *(const f32x8*)(src + (size_t)idx * 8);
    u16x8 o;
    #pragma unroll
    for (int e = 0; e < 8; e++) o[e] = f2bf(v[e]);
    *(u16x8*)(dst + (size_t)idx * 8) = o;
  }
}

// ---------------------------------------------------------------- NT GEMM (m97 structure)
template<bool FP32OUT>
__global__ __launch_bounds__(256) void gemm_nt(
    const u16* __restrict__ A, const u16* __restrict__ B,
    void* __restrict__ Cout, const float* __restrict__ bias,
    int M, int N, int K)
{
  __shared__ u16 As[128 * 32];
  __shared__ u16 Bs[128 * 32];
  const int tid = threadIdx.x;
  const int lane = tid & 63;
  const int wid = tid >> 6;
  const int wr = wid >> 1, wc = wid & 1;
  const int row0 = blockIdx.y * 128, col0 = blockIdx.x * 128;

  const u16* Ag = A + (size_t)(row0 + (tid >> 2)) * K + (tid & 3) * 8;
  const u16* Bg = B + (size_t)(col0 + (tid >> 2)) * K + (tid & 3) * 8;
  u16* AsW0 = As + wid * 512;
  u16* AsW1 = As + 2048 + wid * 512;
  u16* BsW0 = Bs + wid * 512;
  u16* BsW1 = Bs + 2048 + wid * 512;

  f32x4 acc[4][4] = {};

  for (int k0 = 0; k0 < K; k0 += 32) {
    gload_lds16(Ag + k0, AsW0);
    gload_lds16(Ag + (size_t)64 * K + k0, AsW1);
    gload_lds16(Bg + k0, BsW0);
    gload_lds16(Bg + (size_t)64 * K + k0, BsW1);
    __syncthreads();
    bf16x8 a[4], b[4];
    #pragma unroll
    for (int mt = 0; mt < 4; mt++)
      a[mt] = *(const bf16x8*)(As + (wr*64 + mt*16 + (lane & 15)) * 32 + (lane >> 4) * 8);
    #pragma unroll
    for (int nt = 0; nt < 4; nt++)
      b[nt] = *(const bf16x8*)(Bs + (wc*64 + nt*16 + (lane & 15)) * 32 + (lane >> 4) * 8);
    #pragma unroll
    for (int mt = 0; mt < 4; mt++)
      #pragma unroll
      for (int nt = 0; nt < 4; nt++)
        acc[mt][nt] = __builtin_amdgcn_mfma_f32_16x16x32_bf16(a[mt], b[nt], acc[mt][nt], 0, 0, 0);
    __syncthreads();
  }

  #pragma unroll
  for (int mt = 0; mt < 4; mt++) {
    #pragma unroll
    for (int nt = 0; nt < 4; nt++) {
      #pragma unroll
      for (int e = 0; e < 4; e++) {
        int r = row0 + wr*64 + mt*16 + (lane >> 4) * 4 + e;
        int c = col0 + wc*64 + nt*16 + (lane & 15);
        if constexpr (FP32OUT) {
          ((float*)Cout)[(size_t)r * N + c] = acc[mt][nt][e] + bias[c];
        } else {
          ((u16*)Cout)[(size_t)r * N + c] = f2bf(acc[mt][nt][e]);
        }
      }
    }
  }
}

// ---------------------------------------------------------------- per-head LayerNorm on Q,K (in place)
__global__ __launch_bounds__(256) void ln_qk(u16* __restrict__ QKV)
{
  const int row = blockIdx.x;
  const int t = threadIdx.x;
  const int h = t >> 4;
  const int e0 = (t & 15) * 8;
  u16* rowp = QKV + (size_t)row * 6144;
  #pragma unroll
  for (int part = 0; part < 2; part++) {
    u16* p = rowp + part * 2048 + h * 128 + e0;
    u16x8 raw = *(const u16x8*)p;
    float v[8]; float s = 0.f, s2 = 0.f;
    #pragma unroll
    for (int e = 0; e < 8; e++) { v[e] = bf2f(raw[e]); s += v[e]; s2 += v[e]*v[e]; }
    #pragma unroll
    for (int m = 1; m < 16; m <<= 1) { s += __shfl_xor(s, m); s2 += __shfl_xor(s2, m); }
    float mu = s * (1.f / 128.f);
    float var = s2 * (1.f / 128.f) - mu * mu;
    float rstd = rsqrtf(var + 1e-5f);
    u16x8 o;
    #pragma unroll
    for (int e = 0; e < 8; e++) o[e] = f2bf((v[e] - mu) * rstd);
    *(u16x8*)p = o;
  }
}

// ---------------------------------------------------------------- V -> Vt [b,h,d,l]
__global__ __launch_bounds__(256) void transpose_v(const u16* __restrict__ QKV, u16* __restrict__ Vt)
{
  __shared__ u16 T[64 * 65];
  const int d0 = blockIdx.x * 64;
  const int l0 = blockIdx.y * 64;
  const int bh = blockIdx.z;
  const int b = bh >> 4, h = bh & 15;
  const int t = threadIdx.x;
  #pragma unroll
  for (int i = 0; i < 2; i++) {
    int c = t + i * 256;
    int l = c >> 3, dc = (c & 7) * 8;
    u16x8 v = *(const u16x8*)(QKV + (size_t)(b*2048 + l0 + l) * 6144 + 4096 + h*128 + d0 + dc);
    #pragma unroll
    for (int e = 0; e < 8; e++) T[l * 65 + dc + e] = v[e];
  }
  __syncthreads();
  #pragma unroll
  for (int i = 0; i < 2; i++) {
    int c = t + i * 256;
    int d = c >> 3, lc = (c & 7) * 8;
    u16x8 o;
    #pragma unroll
    for (int e = 0; e < 8; e++) o[e] = T[(lc + e) * 65 + d];
    *(u16x8*)(Vt + (size_t)((b*16 + h) * 128 + d0 + d) * 2048 + l0 + lc) = o;
  }
}

// ---------------------------------------------------------------- attn staging helpers
// Pre-swizzled-source global_load_lds (linear LDS dest; source XOR'd by the
// read-side swizzle involution (row&7)<<4 — rule #21 both-sides pattern).
// K tile: 64 rows x 256 B. V^T tile: 128 rows x 128 B.
static __device__ __forceinline__ void stage_k_tile(
    const u16* __restrict__ QKV, int b, int h, int j0, u16* Kbuf, int tid, int wid)
{
  #pragma unroll
  for (int i = 0; i < 4; i++) {
    int c = i * 256 + tid;
    int r = c >> 4, ob = (c & 15) * 16;
    int cb = ob ^ ((r & 7) << 4);
    const u16* g = QKV + (size_t)(b*2048 + j0 + r) * 6144 + 2048 + h*128 + (cb >> 1);
    gload_lds16(g, Kbuf + (i * 256 + wid * 64) * 8);   // wave-uniform LDS base
  }
}
static __device__ __forceinline__ void stage_v_tile(
    const u16* __restrict__ Vt, int b, int h, int j0, u16* Vbuf, int tid, int wid)
{
  #pragma unroll
  for (int i = 0; i < 4; i++) {
    int c = i * 256 + tid;
    int r = c >> 3, ob = (c & 7) * 16;
    int cb = ob ^ ((r & 7) << 4);
    const u16* g = Vt + (size_t)((b*16 + h) * 128 + r) * 2048 + j0 + (cb >> 1);
    gload_lds16(g, Vbuf + (i * 256 + wid * 64) * 8);
  }
}

// ---------------------------------------------------------------- causal flash attention
// Pairing for causal balance: block `pair` does q-tiles pair and 31-pair
// (33 KV-tile iters each; 512 equal blocks = 2/CU).
// K double-buffered via global_load_lds + counted vmcnt(4); V single-buffered.
// Q lives in registers only (loaded once per side). LDS = 56 KB.
__global__ __launch_bounds__(256) void attn(
    const u16* __restrict__ QKV, const u16* __restrict__ Vt, u16* __restrict__ AO)
{
  const int pair = blockIdx.x;   // 0..15
  const int h  = blockIdx.y;     // 0..15
  const int b  = blockIdx.z;     // 0..1
  const int tid = threadIdx.x, lane = tid & 63, wid = tid >> 6;

  __shared__ u16 Ks[2][64 * 128];
  __shared__ u16 Vs[128 * 64];
  __shared__ u16 Ps[4][16 * 64];

  const float SC = 0.08838834764831845f * 1.4426950408889634f;  // 1/sqrt(128) * log2(e)

  for (int side = 0; side < 2; side++) {
    const int pp = side ? (31 - pair) : pair;
    const int l0 = pp * 64;
    const int ntile = pp + 1;

    // Q fragments straight from global (once per side; L2-resident)
    bf16x8 qa[4];
    const u16* qrow = QKV + (size_t)(b*2048 + l0 + wid*16 + (lane & 15)) * 6144
                      + h*128 + (lane >> 4) * 8;
    #pragma unroll
    for (int ks = 0; ks < 4; ks++) qa[ks] = *(const bf16x8*)(qrow + ks * 32);

    f32x4 o[8] = {};
    float mrun[4] = {-1e30f, -1e30f, -1e30f, -1e30f};
    float lrun[4] = {};

    stage_k_tile(QKV, b, h, 0, Ks[0], tid, wid);
    int cur = 0;

    for (int t = 0; t < ntile; t++) {
      const int j0 = t * 64;
      stage_v_tile(Vt, b, h, j0, Vs, tid, wid);
      if (t + 1 < ntile) {
        stage_k_tile(QKV, b, h, j0 + 64, Ks[cur ^ 1], tid, wid);
        // wait K(t)+V(t); leave the 4 newest (K(t+1)) in flight across the barrier
        asm volatile("s_waitcnt vmcnt(4)" ::: "memory");
      } else {
        asm volatile("s_waitcnt vmcnt(0)" ::: "memory");
      }
      __builtin_amdgcn_s_barrier();
      asm volatile("" ::: "memory");

      // ---- S = Q K^T (per wave 16x64)
      f32x4 s[4] = {};
      const char* Kc = (const char*)Ks[cur];
      __builtin_amdgcn_s_setprio(1);
      #pragma unroll
      for (int nt = 0; nt < 4; nt++) {
        #pragma unroll
        for (int ks = 0; ks < 4; ks++) {
          int r = nt * 16 + (lane & 15);
          int cb = ks * 64 + (lane >> 4) * 16;
          bf16x8 kb = *(const bf16x8*)(Kc + r * 256 + (cb ^ ((lane & 7) << 4)));
          s[nt] = __builtin_amdgcn_mfma_f32_16x16x32_bf16(qa[ks], kb, s[nt], 0, 0, 0);
        }
      }
      __builtin_amdgcn_s_setprio(0);

      // ---- scale + causal mask (diagonal tile only: j0 == l0)
      const bool diag = (t == ntile - 1);
      #pragma unroll
      for (int nt = 0; nt < 4; nt++) {
        #pragma unroll
        for (int e = 0; e < 4; e++) {
          float v = s[nt][e] * SC;
          if (diag) {
            int i_loc = wid * 16 + (lane >> 4) * 4 + e;
            int j_loc = nt * 16 + (lane & 15);
            if (j_loc > i_loc) v = -1e30f;
          }
          s[nt][e] = v;
        }
      }

      // ---- online softmax (rows live on 16-lane groups)
      float alpha[4];
      #pragma unroll
      for (int e = 0; e < 4; e++) {
        float v = fmaxf(fmaxf(s[0][e], s[1][e]), fmaxf(s[2][e], s[3][e]));
        v = fmaxf(v, __shfl_xor(v, 1));
        v = fmaxf(v, __shfl_xor(v, 2));
        v = fmaxf(v, __shfl_xor(v, 4));
        v = fmaxf(v, __shfl_xor(v, 8));
        float mi = fmaxf(mrun[e], v);
        alpha[e] = exp2f(mrun[e] - mi);
        mrun[e] = mi;
      }
      float rs[4] = {};
      #pragma unroll
      for (int nt = 0; nt < 4; nt++)
        #pragma unroll
        for (int e = 0; e < 4; e++) {
          float p = exp2f(s[nt][e] - mrun[e]);
          s[nt][e] = p;
          rs[e] += p;
        }
      #pragma unroll
      for (int e = 0; e < 4; e++) {
        rs[e] += __shfl_xor(rs[e], 1);
        rs[e] += __shfl_xor(rs[e], 2);
        rs[e] += __shfl_xor(rs[e], 4);
        rs[e] += __shfl_xor(rs[e], 8);
        lrun[e] = lrun[e] * alpha[e] + rs[e];
      }
      #pragma unroll
      for (int dt = 0; dt < 8; dt++)
        #pragma unroll
        for (int e = 0; e < 4; e++)
          o[dt][e] *= alpha[e];

      // ---- P -> per-wave LDS (swizzled) for PV A-operand redistribution
      char* PsW = (char*)Ps[wid];
      #pragma unroll
      for (int nt = 0; nt < 4; nt++)
        #pragma unroll
        for (int e = 0; e < 4; e++) {
          int i_ = (lane >> 4) * 4 + e;
          int jb = (nt * 16 + (lane & 15)) * 2;
          *(u16*)(PsW + i_ * 128 + (jb ^ ((i_ & 7) << 4))) = f2bf(s[nt][e]);
        }

      // ---- O += P V
      __builtin_amdgcn_s_setprio(1);
      #pragma unroll
      for (int ks = 0; ks < 2; ks++) {
        int ir = lane & 15;
        int jb = ks * 64 + (lane >> 4) * 16;
        bf16x8 pa = *(const bf16x8*)(PsW + ir * 128 + (jb ^ ((ir & 7) << 4)));
        #pragma unroll
        for (int dt = 0; dt < 8; dt++) {
          int dr = dt * 16 + (lane & 15);
          bf16x8 vb = *(const bf16x8*)((const char*)Vs + dr * 128 + (jb ^ ((lane & 7) << 4)));
          o[dt] = __builtin_amdgcn_mfma_f32_16x16x32_bf16(pa, vb, o[dt], 0, 0, 0);
        }
      }
      __builtin_amdgcn_s_setprio(0);

      // end-of-iter barrier: all LDS reads drained before next stage overwrites
      asm volatile("s_waitcnt lgkmcnt(0)" ::: "memory");
      __builtin_amdgcn_s_barrier();
      asm volatile("" ::: "memory");
      cur ^= 1;
    }

    // ---- epilogue
    #pragma unroll
    for (int e = 0; e < 4; e++) {
      float inv = 1.0f / lrun[e];
      int rglob = b * 2048 + l0 + wid * 16 + (lane >> 4) * 4 + e;
      #pragma unroll
      for (int dt = 0; dt < 8; dt++)
        AO[(size_t)rglob * 2048 + h * 128 + dt * 16 + (lane & 15)] = f2bf(o[dt][e] * inv);
    }
  }
}

// ---------------------------------------------------------------- launch
extern "C" void kernel_launch(void* const* d_in, const int* in_sizes, int n_in,
                              void* d_out, int out_size, void* d_ws, size_t ws_size,
                              hipStream_t stream)
{
  const float* x  = (const float*)d_in[0];
  const float* Wq = (const float*)d_in[1];
  const float* Wk = (const float*)d_in[2];
  const float* Wv = (const float*)d_in[3];
  const float* Wo = (const float*)d_in[4];
  const float* bo = (const float*)d_in[5];

  char* ws = (char*)d_ws;
  u16* xb   = (u16*)(ws);
  u16* Wcat = (u16*)(ws + 16777216);
  u16* Wob  = (u16*)(ws + 16777216 + 25165824);
  u16* QKV  = (u16*)(ws + 16777216 + 25165824 + 8388608);
  u16* AO   = xb;
  u16* Vt   = Wcat;

  cast_all<<<dim3(2048), dim3(256), 0, stream>>>(x, Wq, Wk, Wv, Wo, xb, Wcat, Wob);
  gemm_nt<false><<<dim3(48, 32), dim3(256), 0, stream>>>(xb, Wcat, (void*)QKV, nullptr, 4096, 6144, 2048);
  ln_qk<<<dim3(4096), dim3(256), 0, stream>>>(QKV);
  transpose_v<<<dim3(2, 32, 32), dim3(256), 0, stream>>>(QKV, Vt);
  attn<<<dim3(16, 16, 2), dim3(256), 0, stream>>>(QKV, Vt, AO);
  gemm_nt<true><<<dim3(16, 32), dim3(256), 0, stream>>>(AO, Wob, d_out, bo, 4096, 2048, 2048);
}

// Round 3
// 306.503 us; speedup vs baseline: 1.6384x; 1.0886x over previous
//
#include <hip/hip_runtime.h>
#include <stdint.h>

typedef unsigned short u16;
typedef __attribute__((ext_vector_type(8))) unsigned short u16x8;
typedef __attribute__((ext_vector_type(8))) __bf16 bf16x8;
typedef __attribute__((ext_vector_type(4))) float f32x4;
typedef __attribute__((ext_vector_type(8))) float f32x8;

#define AS_G __attribute__((address_space(1)))
#define AS_L __attribute__((address_space(3)))

static __device__ __forceinline__ void gload_lds16(const u16* g, u16* l) {
  __builtin_amdgcn_global_load_lds((AS_G void*)(u16*)g, (AS_L void*)l, 16, 0, 0);
}

static __device__ __forceinline__ u16 f2bf(float f) {
  union { float f; unsigned u; } v; v.f = f;
  return (u16)((v.u + 0x7FFFu + ((v.u >> 16) & 1u)) >> 16);
}
static __device__ __forceinline__ float bf2f(u16 b) {
  union { unsigned u; float f; } v; v.u = ((unsigned)b) << 16;
  return v.f;
}

#define BAR() do { asm volatile("" ::: "memory"); __builtin_amdgcn_s_barrier(); asm volatile("" ::: "memory"); } while (0)

// ---------------------------------------------------------------- cast fp32->bf16
__global__ __launch_bounds__(256) void cast_all(
    const float* __restrict__ x, const float* __restrict__ Wq,
    const float* __restrict__ Wk, const float* __restrict__ Wv,
    const float* __restrict__ Wo,
    u16* __restrict__ xb, u16* __restrict__ Wcat, u16* __restrict__ Wob)
{
  const int NX = (4096 * 2048) / 8;
  const int NW = (2048 * 2048) / 8;
  const int total = NX + 4 * NW;
  for (int i = blockIdx.x * 256 + threadIdx.x; i < total; i += gridDim.x * 256) {
    const float* src; u16* dst; int idx;
    if (i < NX)               { src = x;  dst = xb;                 idx = i; }
    else if (i < NX + NW)     { src = Wq; dst = Wcat;               idx = i - NX; }
    else if (i < NX + 2*NW)   { src = Wk; dst = Wcat + 2048*2048;   idx = i - NX - NW; }
    else if (i < NX + 3*NW)   { src = Wv; dst = Wcat + 2*2048*2048; idx = i - NX - 2*NW; }
    else                      { src = Wo; dst = Wob;                idx = i - NX - 3*NW; }
    f32x8 v = *(const f32x8*)(src + (size_t)idx * 8);
    u16x8 o;
    #pragma unroll
    for (int e = 0; e < 8; e++) o[e] = f2bf(v[e]);
    *(u16x8*)(dst + (size_t)idx * 8) = o;
  }
}

// ---------------------------------------------------------------- 256^2 8-phase NT GEMM
// C[i][j] = sum_k A[i][k]*B[j][k]. BM=BN=256, BK=64, 512 thr (8 waves 2Mx4N).
// LDS: 2 dbuf x (A 256x64 + B 256x64) bf16 = 128 KB, XOR-swizzled (row&7)<<4
// via pre-swizzled global source (linear LDS dest, rule #21 both-sides).
// Schedule: 4 phases/K-tile {ds_read subtile; barrier; stage 1 half-region;
// 16 MFMA(setprio)}; counted vmcnt(4) only at phases 4/8. Region-retirement:
// B(buf) retires after phase0, A(buf) after phase3; every stage targets a
// region retired >=1 barrier earlier.
#define MFMA2(q, x00, x01, x10, x11) \
  do { __builtin_amdgcn_s_setprio(1); \
    _Pragma("unroll") \
    for (int nf = 0; nf < 4; ++nf) { \
      acc[2*(q)][nf]   = __builtin_amdgcn_mfma_f32_16x16x32_bf16(x00, breg[nf][0], acc[2*(q)][nf], 0, 0, 0); \
      acc[2*(q)][nf]   = __builtin_amdgcn_mfma_f32_16x16x32_bf16(x01, breg[nf][1], acc[2*(q)][nf], 0, 0, 0); \
      acc[2*(q)+1][nf] = __builtin_amdgcn_mfma_f32_16x16x32_bf16(x10, breg[nf][0], acc[2*(q)+1][nf], 0, 0, 0); \
      acc[2*(q)+1][nf] = __builtin_amdgcn_mfma_f32_16x16x32_bf16(x11, breg[nf][1], acc[2*(q)+1][nf], 0, 0, 0); \
    } \
    __builtin_amdgcn_s_setprio(0); } while (0)

template<bool FP32OUT>
__global__ __launch_bounds__(512, 2) void gemm256(
    const u16* __restrict__ A, const u16* __restrict__ B,
    void* __restrict__ Cout, const float* __restrict__ bias,
    int M, int N, int K)
{
  __shared__ u16 As[2][256 * 64];
  __shared__ u16 Bs[2][256 * 64];
  const int tid = threadIdx.x, lane = tid & 63, wid = tid >> 6;
  const int wm = wid >> 2, wn = wid & 3;
  const int row0 = blockIdx.y * 256, col0 = blockIdx.x * 256;
  const int NT = K >> 6;          // K-tiles of 64 (must be even)

  // staging address precompute: thread t covers row sr (+64 on 2nd load), 16 B at
  // swizzled source col scb; LDS dest linear (wave-uniform base + lane*16).
  const int sr  = tid >> 3;                    // 0..63
  const int sob = (tid & 7) * 16;              // 0..112
  const int scb = sob ^ ((sr & 7) << 4);

  auto stA = [&](int buf, int t, int half) {
    const u16* src = A + (size_t)(row0 + half * 128 + sr) * K + t * 64 + (scb >> 1);
    u16* dst = As[buf] + half * 8192 + wid * 512;
    gload_lds16(src, dst);
    gload_lds16(src + (size_t)64 * K, dst + 4096);
  };
  auto stB = [&](int buf, int t, int half) {
    const u16* src = B + (size_t)(col0 + half * 128 + sr) * K + t * 64 + (scb >> 1);
    u16* dst = Bs[buf] + half * 8192 + wid * 512;
    gload_lds16(src, dst);
    gload_lds16(src + (size_t)64 * K, dst + 4096);
  };
  auto ldA = [&](int buf, int mf, int k) {
    int ra = wm * 128 + mf * 16 + (lane & 15);
    int bc = k * 64 + ((lane >> 4) << 4);
    return *(const bf16x8*)((const char*)As[buf] + ra * 128 + (bc ^ ((ra & 7) << 4)));
  };
  auto ldB = [&](int buf, int nf, int k) {
    int rb = wn * 64 + nf * 16 + (lane & 15);
    int bc = k * 64 + ((lane >> 4) << 4);
    return *(const bf16x8*)((const char*)Bs[buf] + rb * 128 + (bc ^ ((rb & 7) << 4)));
  };

  f32x4 acc[8][4] = {};
  bf16x8 breg[4][2];

  // prologue: tile0 fully -> buf0; B(tile1) -> buf1 (A(tile1) staged in phases 0/1)
  stA(0, 0, 0); stA(0, 0, 1); stB(0, 0, 0); stB(0, 0, 1);
  stB(1, 1, 0); stB(1, 1, 1);
  asm volatile("s_waitcnt vmcnt(4)" ::: "memory");
  BAR();

  for (int it = 0; it < NT / 2; ++it) {
    const int t1  = 2 * it + 1;
    const int pf0 = (2 * it + 2 < NT) ? (2 * it + 2) : (NT - 1);
    const int pf1 = (2 * it + 3 < NT) ? (2 * it + 3) : (NT - 1);
    #pragma unroll
    for (int hf = 0; hf < 2; ++hf) {
      const int cb = hf;
      // ---- phase 0: read all B-frags + A mf0,1 ; stage A-half0(next tile)
      #pragma unroll
      for (int nf = 0; nf < 4; ++nf) {
        breg[nf][0] = ldB(cb, nf, 0);
        breg[nf][1] = ldB(cb, nf, 1);
      }
      bf16x8 a00 = ldA(cb, 0, 0), a01 = ldA(cb, 0, 1);
      bf16x8 a10 = ldA(cb, 1, 0), a11 = ldA(cb, 1, 1);
      BAR();
      if (hf == 0) stA(1, t1, 0); else stA(0, pf0, 0);
      MFMA2(0, a00, a01, a10, a11);
      // ---- phase 1: A mf2,3 ; stage A-half1(next tile)
      a00 = ldA(cb, 2, 0); a01 = ldA(cb, 2, 1);
      a10 = ldA(cb, 3, 0); a11 = ldA(cb, 3, 1);
      BAR();
      if (hf == 0) stA(1, t1, 1); else stA(0, pf0, 1);
      MFMA2(1, a00, a01, a10, a11);
      // ---- phase 2: A mf4,5 ; stage B-half0(tile+2)  [B(cb) retired at phase0]
      a00 = ldA(cb, 4, 0); a01 = ldA(cb, 4, 1);
      a10 = ldA(cb, 5, 0); a11 = ldA(cb, 5, 1);
      BAR();
      if (hf == 0) stB(0, pf0, 0); else stB(1, pf1, 0);
      MFMA2(2, a00, a01, a10, a11);
      // ---- phase 3: A mf6,7 ; stage B-half1(tile+2)
      a00 = ldA(cb, 6, 0); a01 = ldA(cb, 6, 1);
      a10 = ldA(cb, 7, 0); a11 = ldA(cb, 7, 1);
      BAR();
      if (hf == 0) stB(0, pf0, 1); else stB(1, pf1, 1);
      MFMA2(3, a00, a01, a10, a11);
      // counted wait: 4 newest (B of tile+2) stay in flight; everything the
      // next phase reads has landed.
      asm volatile("s_waitcnt vmcnt(4)" ::: "memory");
      BAR();
    }
  }
  asm volatile("s_waitcnt vmcnt(0)" ::: "memory");  // don't exit with LDS-writing loads in flight

  #pragma unroll
  for (int mf = 0; mf < 8; ++mf) {
    #pragma unroll
    for (int nf = 0; nf < 4; ++nf) {
      #pragma unroll
      for (int e = 0; e < 4; ++e) {
        int r = row0 + wm * 128 + mf * 16 + (lane >> 4) * 4 + e;
        int c = col0 + wn * 64 + nf * 16 + (lane & 15);
        if constexpr (FP32OUT) {
          ((float*)Cout)[(size_t)r * N + c] = acc[mf][nf][e] + bias[c];
        } else {
          ((u16*)Cout)[(size_t)r * N + c] = f2bf(acc[mf][nf][e]);
        }
      }
    }
  }
}

// ---------------------------------------------------------------- NT GEMM (m97 structure; kept for AO @ N=2048)
template<bool FP32OUT>
__global__ __launch_bounds__(256) void gemm_nt(
    const u16* __restrict__ A, const u16* __restrict__ B,
    void* __restrict__ Cout, const float* __restrict__ bias,
    int M, int N, int K)
{
  __shared__ u16 As[128 * 32];
  __shared__ u16 Bs[128 * 32];
  const int tid = threadIdx.x;
  const int lane = tid & 63;
  const int wid = tid >> 6;
  const int wr = wid >> 1, wc = wid & 1;
  const int row0 = blockIdx.y * 128, col0 = blockIdx.x * 128;

  const u16* Ag = A + (size_t)(row0 + (tid >> 2)) * K + (tid & 3) * 8;
  const u16* Bg = B + (size_t)(col0 + (tid >> 2)) * K + (tid & 3) * 8;
  u16* AsW0 = As + wid * 512;
  u16* AsW1 = As + 2048 + wid * 512;
  u16* BsW0 = Bs + wid * 512;
  u16* BsW1 = Bs + 2048 + wid * 512;

  f32x4 acc[4][4] = {};

  for (int k0 = 0; k0 < K; k0 += 32) {
    gload_lds16(Ag + k0, AsW0);
    gload_lds16(Ag + (size_t)64 * K + k0, AsW1);
    gload_lds16(Bg + k0, BsW0);
    gload_lds16(Bg + (size_t)64 * K + k0, BsW1);
    __syncthreads();
    bf16x8 a[4], b[4];
    #pragma unroll
    for (int mt = 0; mt < 4; mt++)
      a[mt] = *(const bf16x8*)(As + (wr*64 + mt*16 + (lane & 15)) * 32 + (lane >> 4) * 8);
    #pragma unroll
    for (int nt = 0; nt < 4; nt++)
      b[nt] = *(const bf16x8*)(Bs + (wc*64 + nt*16 + (lane & 15)) * 32 + (lane >> 4) * 8);
    #pragma unroll
    for (int mt = 0; mt < 4; mt++)
      #pragma unroll
      for (int nt = 0; nt < 4; nt++)
        acc[mt][nt] = __builtin_amdgcn_mfma_f32_16x16x32_bf16(a[mt], b[nt], acc[mt][nt], 0, 0, 0);
    __syncthreads();
  }

  #pragma unroll
  for (int mt = 0; mt < 4; mt++) {
    #pragma unroll
    for (int nt = 0; nt < 4; nt++) {
      #pragma unroll
      for (int e = 0; e < 4; e++) {
        int r = row0 + wr*64 + mt*16 + (lane >> 4) * 4 + e;
        int c = col0 + wc*64 + nt*16 + (lane & 15);
        if constexpr (FP32OUT) {
          ((float*)Cout)[(size_t)r * N + c] = acc[mt][nt][e] + bias[c];
        } else {
          ((u16*)Cout)[(size_t)r * N + c] = f2bf(acc[mt][nt][e]);
        }
      }
    }
  }
}

// ---------------------------------------------------------------- per-head LayerNorm on Q,K (in place)
__global__ __launch_bounds__(256) void ln_qk(u16* __restrict__ QKV)
{
  const int row = blockIdx.x;
  const int t = threadIdx.x;
  const int h = t >> 4;
  const int e0 = (t & 15) * 8;
  u16* rowp = QKV + (size_t)row * 6144;
  #pragma unroll
  for (int part = 0; part < 2; part++) {
    u16* p = rowp + part * 2048 + h * 128 + e0;
    u16x8 raw = *(const u16x8*)p;
    float v[8]; float s = 0.f, s2 = 0.f;
    #pragma unroll
    for (int e = 0; e < 8; e++) { v[e] = bf2f(raw[e]); s += v[e]; s2 += v[e]*v[e]; }
    #pragma unroll
    for (int m = 1; m < 16; m <<= 1) { s += __shfl_xor(s, m); s2 += __shfl_xor(s2, m); }
    float mu = s * (1.f / 128.f);
    float var = s2 * (1.f / 128.f) - mu * mu;
    float rstd = rsqrtf(var + 1e-5f);
    u16x8 o;
    #pragma unroll
    for (int e = 0; e < 8; e++) o[e] = f2bf((v[e] - mu) * rstd);
    *(u16x8*)p = o;
  }
}

// ---------------------------------------------------------------- V -> Vt [b,h,d,l]
__global__ __launch_bounds__(256) void transpose_v(const u16* __restrict__ QKV, u16* __restrict__ Vt)
{
  __shared__ u16 T[64 * 65];
  const int d0 = blockIdx.x * 64;
  const int l0 = blockIdx.y * 64;
  const int bh = blockIdx.z;
  const int b = bh >> 4, h = bh & 15;
  const int t = threadIdx.x;
  #pragma unroll
  for (int i = 0; i < 2; i++) {
    int c = t + i * 256;
    int l = c >> 3, dc = (c & 7) * 8;
    u16x8 v = *(const u16x8*)(QKV + (size_t)(b*2048 + l0 + l) * 6144 + 4096 + h*128 + d0 + dc);
    #pragma unroll
    for (int e = 0; e < 8; e++) T[l * 65 + dc + e] = v[e];
  }
  __syncthreads();
  #pragma unroll
  for (int i = 0; i < 2; i++) {
    int c = t + i * 256;
    int d = c >> 3, lc = (c & 7) * 8;
    u16x8 o;
    #pragma unroll
    for (int e = 0; e < 8; e++) o[e] = T[(lc + e) * 65 + d];
    *(u16x8*)(Vt + (size_t)((b*16 + h) * 128 + d0 + d) * 2048 + l0 + lc) = o;
  }
}

// ---------------------------------------------------------------- attn staging helpers
static __device__ __forceinline__ void stage_k_tile(
    const u16* __restrict__ QKV, int b, int h, int j0, u16* Kbuf, int tid, int wid)
{
  #pragma unroll
  for (int i = 0; i < 4; i++) {
    int c = i * 256 + tid;
    int r = c >> 4, ob = (c & 15) * 16;
    int cb = ob ^ ((r & 7) << 4);
    const u16* g = QKV + (size_t)(b*2048 + j0 + r) * 6144 + 2048 + h*128 + (cb >> 1);
    gload_lds16(g, Kbuf + (i * 256 + wid * 64) * 8);
  }
}
static __device__ __forceinline__ void stage_v_tile(
    const u16* __restrict__ Vt, int b, int h, int j0, u16* Vbuf, int tid, int wid)
{
  #pragma unroll
  for (int i = 0; i < 4; i++) {
    int c = i * 256 + tid;
    int r = c >> 3, ob = (c & 7) * 16;
    int cb = ob ^ ((r & 7) << 4);
    const u16* g = Vt + (size_t)((b*16 + h) * 128 + r) * 2048 + j0 + (cb >> 1);
    gload_lds16(g, Vbuf + (i * 256 + wid * 64) * 8);
  }
}

// ---------------------------------------------------------------- causal flash attention
__global__ __launch_bounds__(256) void attn(
    const u16* __restrict__ QKV, const u16* __restrict__ Vt, u16* __restrict__ AO)
{
  const int pair = blockIdx.x;
  const int h  = blockIdx.y;
  const int b  = blockIdx.z;
  const int tid = threadIdx.x, lane = tid & 63, wid = tid >> 6;

  __shared__ u16 Ks[2][64 * 128];
  __shared__ u16 Vs[128 * 64];
  __shared__ u16 Ps[4][16 * 64];

  const float SC = 0.08838834764831845f * 1.4426950408889634f;

  for (int side = 0; side < 2; side++) {
    const int pp = side ? (31 - pair) : pair;
    const int l0 = pp * 64;
    const int ntile = pp + 1;

    bf16x8 qa[4];
    const u16* qrow = QKV + (size_t)(b*2048 + l0 + wid*16 + (lane & 15)) * 6144
                      + h*128 + (lane >> 4) * 8;
    #pragma unroll
    for (int ks = 0; ks < 4; ks++) qa[ks] = *(const bf16x8*)(qrow + ks * 32);

    f32x4 o[8] = {};
    float mrun[4] = {-1e30f, -1e30f, -1e30f, -1e30f};
    float lrun[4] = {};

    stage_k_tile(QKV, b, h, 0, Ks[0], tid, wid);
    int cur = 0;

    for (int t = 0; t < ntile; t++) {
      const int j0 = t * 64;
      stage_v_tile(Vt, b, h, j0, Vs, tid, wid);
      if (t + 1 < ntile) {
        stage_k_tile(QKV, b, h, j0 + 64, Ks[cur ^ 1], tid, wid);
        asm volatile("s_waitcnt vmcnt(4)" ::: "memory");
      } else {
        asm volatile("s_waitcnt vmcnt(0)" ::: "memory");
      }
      __builtin_amdgcn_s_barrier();
      asm volatile("" ::: "memory");

      f32x4 s[4] = {};
      const char* Kc = (const char*)Ks[cur];
      __builtin_amdgcn_s_setprio(1);
      #pragma unroll
      for (int nt = 0; nt < 4; nt++) {
        #pragma unroll
        for (int ks = 0; ks < 4; ks++) {
          int r = nt * 16 + (lane & 15);
          int cb = ks * 64 + (lane >> 4) * 16;
          bf16x8 kb = *(const bf16x8*)(Kc + r * 256 + (cb ^ ((lane & 7) << 4)));
          s[nt] = __builtin_amdgcn_mfma_f32_16x16x32_bf16(qa[ks], kb, s[nt], 0, 0, 0);
        }
      }
      __builtin_amdgcn_s_setprio(0);

      const bool diag = (t == ntile - 1);
      #pragma unroll
      for (int nt = 0; nt < 4; nt++) {
        #pragma unroll
        for (int e = 0; e < 4; e++) {
          float v = s[nt][e] * SC;
          if (diag) {
            int i_loc = wid * 16 + (lane >> 4) * 4 + e;
            int j_loc = nt * 16 + (lane & 15);
            if (j_loc > i_loc) v = -1e30f;
          }
          s[nt][e] = v;
        }
      }

      float alpha[4];
      #pragma unroll
      for (int e = 0; e < 4; e++) {
        float v = fmaxf(fmaxf(s[0][e], s[1][e]), fmaxf(s[2][e], s[3][e]));
        v = fmaxf(v, __shfl_xor(v, 1));
        v = fmaxf(v, __shfl_xor(v, 2));
        v = fmaxf(v, __shfl_xor(v, 4));
        v = fmaxf(v, __shfl_xor(v, 8));
        float mi = fmaxf(mrun[e], v);
        alpha[e] = exp2f(mrun[e] - mi);
        mrun[e] = mi;
      }
      float rs[4] = {};
      #pragma unroll
      for (int nt = 0; nt < 4; nt++)
        #pragma unroll
        for (int e = 0; e < 4; e++) {
          float p = exp2f(s[nt][e] - mrun[e]);
          s[nt][e] = p;
          rs[e] += p;
        }
      #pragma unroll
      for (int e = 0; e < 4; e++) {
        rs[e] += __shfl_xor(rs[e], 1);
        rs[e] += __shfl_xor(rs[e], 2);
        rs[e] += __shfl_xor(rs[e], 4);
        rs[e] += __shfl_xor(rs[e], 8);
        lrun[e] = lrun[e] * alpha[e] + rs[e];
      }
      #pragma unroll
      for (int dt = 0; dt < 8; dt++)
        #pragma unroll
        for (int e = 0; e < 4; e++)
          o[dt][e] *= alpha[e];

      char* PsW = (char*)Ps[wid];
      #pragma unroll
      for (int nt = 0; nt < 4; nt++)
        #pragma unroll
        for (int e = 0; e < 4; e++) {
          int i_ = (lane >> 4) * 4 + e;
          int jb = (nt * 16 + (lane & 15)) * 2;
          *(u16*)(PsW + i_ * 128 + (jb ^ ((i_ & 7) << 4))) = f2bf(s[nt][e]);
        }

      __builtin_amdgcn_s_setprio(1);
      #pragma unroll
      for (int ks = 0; ks < 2; ks++) {
        int ir = lane & 15;
        int jb = ks * 64 + (lane >> 4) * 16;
        bf16x8 pa = *(const bf16x8*)(PsW + ir * 128 + (jb ^ ((ir & 7) << 4)));
        #pragma unroll
        for (int dt = 0; dt < 8; dt++) {
          int dr = dt * 16 + (lane & 15);
          bf16x8 vb = *(const bf16x8*)((const char*)Vs + dr * 128 + (jb ^ ((lane & 7) << 4)));
          o[dt] = __builtin_amdgcn_mfma_f32_16x16x32_bf16(pa, vb, o[dt], 0, 0, 0);
        }
      }
      __builtin_amdgcn_s_setprio(0);

      asm volatile("s_waitcnt lgkmcnt(0)" ::: "memory");
      __builtin_amdgcn_s_barrier();
      asm volatile("" ::: "memory");
      cur ^= 1;
    }

    #pragma unroll
    for (int e = 0; e < 4; e++) {
      float inv = 1.0f / lrun[e];
      int rglob = b * 2048 + l0 + wid * 16 + (lane >> 4) * 4 + e;
      #pragma unroll
      for (int dt = 0; dt < 8; dt++)
        AO[(size_t)rglob * 2048 + h * 128 + dt * 16 + (lane & 15)] = f2bf(o[dt][e] * inv);
    }
  }
}

// ---------------------------------------------------------------- launch
extern "C" void kernel_launch(void* const* d_in, const int* in_sizes, int n_in,
                              void* d_out, int out_size, void* d_ws, size_t ws_size,
                              hipStream_t stream)
{
  const float* x  = (const float*)d_in[0];
  const float* Wq = (const float*)d_in[1];
  const float* Wk = (const float*)d_in[2];
  const float* Wv = (const float*)d_in[3];
  const float* Wo = (const float*)d_in[4];
  const float* bo = (const float*)d_in[5];

  char* ws = (char*)d_ws;
  u16* xb   = (u16*)(ws);
  u16* Wcat = (u16*)(ws + 16777216);
  u16* Wob  = (u16*)(ws + 16777216 + 25165824);
  u16* QKV  = (u16*)(ws + 16777216 + 25165824 + 8388608);
  u16* AO   = xb;
  u16* Vt   = Wcat;

  cast_all<<<dim3(2048), dim3(256), 0, stream>>>(x, Wq, Wk, Wv, Wo, xb, Wcat, Wob);
  gemm256<false><<<dim3(24, 16), dim3(512), 0, stream>>>(xb, Wcat, (void*)QKV, nullptr, 4096, 6144, 2048);
  ln_qk<<<dim3(4096), dim3(256), 0, stream>>>(QKV);
  transpose_v<<<dim3(2, 32, 32), dim3(256), 0, stream>>>(QKV, Vt);
  attn<<<dim3(16, 16, 2), dim3(256), 0, stream>>>(QKV, Vt, AO);
  gemm_nt<true><<<dim3(16, 32), dim3(256), 0, stream>>>(AO, Wob, d_out, bo, 4096, 2048, 2048);
}

// Round 4
// 295.091 us; speedup vs baseline: 1.7018x; 1.0387x over previous
//
#include <hip/hip_runtime.h>
#include <stdint.h>

typedef unsigned short u16;
typedef __attribute__((ext_vector_type(8))) unsigned short u16x8;
typedef __attribute__((ext_vector_type(8))) __bf16 bf16x8;
typedef __attribute__((ext_vector_type(4))) float f32x4;
typedef __attribute__((ext_vector_type(8))) float f32x8;

#define AS_G __attribute__((address_space(1)))
#define AS_L __attribute__((address_space(3)))

static __device__ __forceinline__ void gload_lds16(const u16* g, u16* l) {
  __builtin_amdgcn_global_load_lds((AS_G void*)(u16*)g, (AS_L void*)l, 16, 0, 0);
}

static __device__ __forceinline__ u16 f2bf(float f) {
  union { float f; unsigned u; } v; v.f = f;
  return (u16)((v.u + 0x7FFFu + ((v.u >> 16) & 1u)) >> 16);
}
static __device__ __forceinline__ float bf2f(u16 b) {
  union { unsigned u; float f; } v; v.u = ((unsigned)b) << 16;
  return v.f;
}
static __device__ __forceinline__ u16 f2bf_trunc(float f) {
  union { float f; unsigned u; } v; v.f = f;
  return (u16)(v.u >> 16);
}

#define BAR() do { asm volatile("" ::: "memory"); __builtin_amdgcn_s_barrier(); asm volatile("" ::: "memory"); } while (0)

// ---------------------------------------------------------------- cast fp32->bf16
__global__ __launch_bounds__(256) void cast_all(
    const float* __restrict__ x, const float* __restrict__ Wq,
    const float* __restrict__ Wk, const float* __restrict__ Wv,
    const float* __restrict__ Wo,
    u16* __restrict__ xb, u16* __restrict__ Wcat, u16* __restrict__ Wob)
{
  const int NX = (4096 * 2048) / 8;
  const int NW = (2048 * 2048) / 8;
  const int total = NX + 4 * NW;
  for (int i = blockIdx.x * 256 + threadIdx.x; i < total; i += gridDim.x * 256) {
    const float* src; u16* dst; int idx;
    if (i < NX)               { src = x;  dst = xb;                 idx = i; }
    else if (i < NX + NW)     { src = Wq; dst = Wcat;               idx = i - NX; }
    else if (i < NX + 2*NW)   { src = Wk; dst = Wcat + 2048*2048;   idx = i - NX - NW; }
    else if (i < NX + 3*NW)   { src = Wv; dst = Wcat + 2*2048*2048; idx = i - NX - 2*NW; }
    else                      { src = Wo; dst = Wob;                idx = i - NX - 3*NW; }
    f32x8 v = *(const f32x8*)(src + (size_t)idx * 8);
    u16x8 o;
    #pragma unroll
    for (int e = 0; e < 8; e++) o[e] = f2bf(v[e]);
    *(u16x8*)(dst + (size_t)idx * 8) = o;
  }
}

// ---------------------------------------------------------------- 256x192 8-phase NT GEMM
// C[i][j] = sum_k A[i][k]*B[j][k]. BM=256, BN=192, BK=64, 512 thr (8 waves 2Mx4N,
// per-wave 128x48). Grid 32x16 = 512 blocks = EXACTLY 2 dispatch rounds of 256 CUs.
// LDS: 2dbuf x (A 32KB + B 24KB) = 112KB, XOR-swizzle (row&7)<<4 both-sides.
// Staging in 64-row units (1 gload/thread): A=4 units, B=3 units per K-tile.
// Phases stage 2/2/2/1 units; vmcnt(3) at tile end (3 newest = next B in flight).
#define MFMA2(q, x00, x01, x10, x11) \
  do { __builtin_amdgcn_s_setprio(1); \
    _Pragma("unroll") \
    for (int nf = 0; nf < 3; ++nf) { \
      acc[2*(q)][nf]   = __builtin_amdgcn_mfma_f32_16x16x32_bf16(x00, breg[nf][0], acc[2*(q)][nf], 0, 0, 0); \
      acc[2*(q)][nf]   = __builtin_amdgcn_mfma_f32_16x16x32_bf16(x01, breg[nf][1], acc[2*(q)][nf], 0, 0, 0); \
      acc[2*(q)+1][nf] = __builtin_amdgcn_mfma_f32_16x16x32_bf16(x10, breg[nf][0], acc[2*(q)+1][nf], 0, 0, 0); \
      acc[2*(q)+1][nf] = __builtin_amdgcn_mfma_f32_16x16x32_bf16(x11, breg[nf][1], acc[2*(q)+1][nf], 0, 0, 0); \
    } \
    __builtin_amdgcn_s_setprio(0); } while (0)

__global__ __launch_bounds__(512, 2) void gemm256(
    const u16* __restrict__ A, const u16* __restrict__ B,
    u16* __restrict__ Cout, int M, int N, int K)
{
  __shared__ u16 As[2][256 * 64];
  __shared__ u16 Bs[2][192 * 64];
  const int tid = threadIdx.x, lane = tid & 63, wid = tid >> 6;
  const int wm = wid >> 2, wn = wid & 3;

  // bijective XCD swizzle (nwg = 32*16 = 512, 512%8==0)
  const int nbx = gridDim.x;
  const int nwg = gridDim.x * gridDim.y;
  const int flat = blockIdx.y * nbx + blockIdx.x;
  const int swz = (flat & 7) * (nwg >> 3) + (flat >> 3);
  const int row0 = (swz / nbx) * 256, col0 = (swz % nbx) * 192;
  const int NT = K >> 6;          // K-tiles of 64 (even)

  const int sr  = tid >> 3;                    // 0..63
  const int scb = ((tid & 7) * 16) ^ ((sr & 7) << 4);

  auto stA = [&](int buf, int t, int u) {
    const u16* src = A + (size_t)(row0 + u * 64 + sr) * K + t * 64 + (scb >> 1);
    gload_lds16(src, As[buf] + u * 4096 + wid * 512);
  };
  auto stB = [&](int buf, int t, int u) {
    const u16* src = B + (size_t)(col0 + u * 64 + sr) * K + t * 64 + (scb >> 1);
    gload_lds16(src, Bs[buf] + u * 4096 + wid * 512);
  };
  auto ldA = [&](int buf, int mf, int k) {
    int ra = wm * 128 + mf * 16 + (lane & 15);
    int bc = (k * 64 + ((lane >> 4) << 4)) ^ ((ra & 7) << 4);
    return *(const bf16x8*)((const char*)As[buf] + ra * 128 + bc);
  };
  auto ldB = [&](int buf, int nf, int k) {
    int rb = wn * 48 + nf * 16 + (lane & 15);
    int bc = (k * 64 + ((lane >> 4) << 4)) ^ ((rb & 7) << 4);
    return *(const bf16x8*)((const char*)Bs[buf] + rb * 128 + bc);
  };

  f32x4 acc[8][3] = {};
  bf16x8 breg[3][2];

  // prologue: tile0 -> buf0 (7 loads); B(tile1) -> buf1 (3 loads)
  stA(0, 0, 0); stA(0, 0, 1); stA(0, 0, 2); stA(0, 0, 3);
  stB(0, 0, 0); stB(0, 0, 1); stB(0, 0, 2);
  stB(1, 1, 0); stB(1, 1, 1); stB(1, 1, 2);
  asm volatile("s_waitcnt vmcnt(3)" ::: "memory");
  BAR();

  for (int it = 0; it < NT / 2; ++it) {
    const int t1  = 2 * it + 1;
    const int pf0 = (2 * it + 2 < NT) ? (2 * it + 2) : (NT - 1);
    const int pf1 = (2 * it + 3 < NT) ? (2 * it + 3) : (NT - 1);
    #pragma unroll
    for (int hf = 0; hf < 2; ++hf) {
      const int cb = hf;
      // ---- phase 0: all B-frags + A mf0,1 ; stage next-A units 0,1
      #pragma unroll
      for (int nf = 0; nf < 3; ++nf) {
        breg[nf][0] = ldB(cb, nf, 0);
        breg[nf][1] = ldB(cb, nf, 1);
      }
      bf16x8 a00 = ldA(cb, 0, 0), a01 = ldA(cb, 0, 1);
      bf16x8 a10 = ldA(cb, 1, 0), a11 = ldA(cb, 1, 1);
      BAR();
      if (hf == 0) { stA(1, t1, 0); stA(1, t1, 1); } else { stA(0, pf0, 0); stA(0, pf0, 1); }
      MFMA2(0, a00, a01, a10, a11);
      // ---- phase 1: A mf2,3 ; stage next-A units 2,3
      a00 = ldA(cb, 2, 0); a01 = ldA(cb, 2, 1);
      a10 = ldA(cb, 3, 0); a11 = ldA(cb, 3, 1);
      BAR();
      if (hf == 0) { stA(1, t1, 2); stA(1, t1, 3); } else { stA(0, pf0, 2); stA(0, pf0, 3); }
      MFMA2(1, a00, a01, a10, a11);
      // ---- phase 2: A mf4,5 ; stage B(+2) units 0,1  [this buf's B retired after phase0]
      a00 = ldA(cb, 4, 0); a01 = ldA(cb, 4, 1);
      a10 = ldA(cb, 5, 0); a11 = ldA(cb, 5, 1);
      BAR();
      if (hf == 0) { stB(0, pf0, 0); stB(0, pf0, 1); } else { stB(1, pf1, 0); stB(1, pf1, 1); }
      MFMA2(2, a00, a01, a10, a11);
      // ---- phase 3: A mf6,7 ; stage B(+2) unit 2
      a00 = ldA(cb, 6, 0); a01 = ldA(cb, 6, 1);
      a10 = ldA(cb, 7, 0); a11 = ldA(cb, 7, 1);
      BAR();
      if (hf == 0) stB(0, pf0, 2); else stB(1, pf1, 2);
      MFMA2(3, a00, a01, a10, a11);
      // counted wait: 3 newest (B of tile+2) stay in flight
      asm volatile("s_waitcnt vmcnt(3)" ::: "memory");
      BAR();
    }
  }
  asm volatile("s_waitcnt vmcnt(0)" ::: "memory");

  #pragma unroll
  for (int mf = 0; mf < 8; ++mf) {
    #pragma unroll
    for (int nf = 0; nf < 3; ++nf) {
      #pragma unroll
      for (int e = 0; e < 4; ++e) {
        int r = row0 + wm * 128 + mf * 16 + (lane >> 4) * 4 + e;
        int c = col0 + wn * 48 + nf * 16 + (lane & 15);
        Cout[(size_t)r * N + c] = f2bf(acc[mf][nf][e]);
      }
    }
  }
}

// ---------------------------------------------------------------- NT GEMM (m97; AO @ N=2048)
template<bool FP32OUT>
__global__ __launch_bounds__(256) void gemm_nt(
    const u16* __restrict__ A, const u16* __restrict__ B,
    void* __restrict__ Cout, const float* __restrict__ bias,
    int M, int N, int K)
{
  __shared__ u16 As[128 * 32];
  __shared__ u16 Bs[128 * 32];
  const int tid = threadIdx.x;
  const int lane = tid & 63;
  const int wid = tid >> 6;
  const int wr = wid >> 1, wc = wid & 1;
  const int row0 = blockIdx.y * 128, col0 = blockIdx.x * 128;

  const u16* Ag = A + (size_t)(row0 + (tid >> 2)) * K + (tid & 3) * 8;
  const u16* Bg = B + (size_t)(col0 + (tid >> 2)) * K + (tid & 3) * 8;
  u16* AsW0 = As + wid * 512;
  u16* AsW1 = As + 2048 + wid * 512;
  u16* BsW0 = Bs + wid * 512;
  u16* BsW1 = Bs + 2048 + wid * 512;

  f32x4 acc[4][4] = {};

  for (int k0 = 0; k0 < K; k0 += 32) {
    gload_lds16(Ag + k0, AsW0);
    gload_lds16(Ag + (size_t)64 * K + k0, AsW1);
    gload_lds16(Bg + k0, BsW0);
    gload_lds16(Bg + (size_t)64 * K + k0, BsW1);
    __syncthreads();
    bf16x8 a[4], b[4];
    #pragma unroll
    for (int mt = 0; mt < 4; mt++)
      a[mt] = *(const bf16x8*)(As + (wr*64 + mt*16 + (lane & 15)) * 32 + (lane >> 4) * 8);
    #pragma unroll
    for (int nt = 0; nt < 4; nt++)
      b[nt] = *(const bf16x8*)(Bs + (wc*64 + nt*16 + (lane & 15)) * 32 + (lane >> 4) * 8);
    #pragma unroll
    for (int mt = 0; mt < 4; mt++)
      #pragma unroll
      for (int nt = 0; nt < 4; nt++)
        acc[mt][nt] = __builtin_amdgcn_mfma_f32_16x16x32_bf16(a[mt], b[nt], acc[mt][nt], 0, 0, 0);
    __syncthreads();
  }

  #pragma unroll
  for (int mt = 0; mt < 4; mt++) {
    #pragma unroll
    for (int nt = 0; nt < 4; nt++) {
      #pragma unroll
      for (int e = 0; e < 4; e++) {
        int r = row0 + wr*64 + mt*16 + (lane >> 4) * 4 + e;
        int c = col0 + wc*64 + nt*16 + (lane & 15);
        if constexpr (FP32OUT) {
          ((float*)Cout)[(size_t)r * N + c] = acc[mt][nt][e] + bias[c];
        } else {
          ((u16*)Cout)[(size_t)r * N + c] = f2bf(acc[mt][nt][e]);
        }
      }
    }
  }
}

// ---------------------------------------------------------------- per-head LayerNorm on Q,K
// Q additionally pre-scaled by 1/sqrt(128)*log2(e) so attn's QK^T lands in
// log2 domain with no per-element multiply.
__global__ __launch_bounds__(256) void ln_qk(u16* __restrict__ QKV)
{
  const float SC2 = 0.08838834764831845f * 1.4426950408889634f;
  const int row = blockIdx.x;
  const int t = threadIdx.x;
  const int h = t >> 4;
  const int e0 = (t & 15) * 8;
  u16* rowp = QKV + (size_t)row * 6144;
  #pragma unroll
  for (int part = 0; part < 2; part++) {
    u16* p = rowp + part * 2048 + h * 128 + e0;
    u16x8 raw = *(const u16x8*)p;
    float v[8]; float s = 0.f, s2 = 0.f;
    #pragma unroll
    for (int e = 0; e < 8; e++) { v[e] = bf2f(raw[e]); s += v[e]; s2 += v[e]*v[e]; }
    #pragma unroll
    for (int m = 1; m < 16; m <<= 1) { s += __shfl_xor(s, m); s2 += __shfl_xor(s2, m); }
    float mu = s * (1.f / 128.f);
    float var = s2 * (1.f / 128.f) - mu * mu;
    float rstd = rsqrtf(var + 1e-5f) * (part == 0 ? SC2 : 1.0f);
    u16x8 o;
    #pragma unroll
    for (int e = 0; e < 8; e++) o[e] = f2bf((v[e] - mu) * rstd);
    *(u16x8*)p = o;
  }
}

// ---------------------------------------------------------------- V -> Vt [b,h,d,l]
__global__ __launch_bounds__(256) void transpose_v(const u16* __restrict__ QKV, u16* __restrict__ Vt)
{
  __shared__ u16 T[64 * 65];
  const int d0 = blockIdx.x * 64;
  const int l0 = blockIdx.y * 64;
  const int bh = blockIdx.z;
  const int b = bh >> 4, h = bh & 15;
  const int t = threadIdx.x;
  #pragma unroll
  for (int i = 0; i < 2; i++) {
    int c = t + i * 256;
    int l = c >> 3, dc = (c & 7) * 8;
    u16x8 v = *(const u16x8*)(QKV + (size_t)(b*2048 + l0 + l) * 6144 + 4096 + h*128 + d0 + dc);
    #pragma unroll
    for (int e = 0; e < 8; e++) T[l * 65 + dc + e] = v[e];
  }
  __syncthreads();
  #pragma unroll
  for (int i = 0; i < 2; i++) {
    int c = t + i * 256;
    int d = c >> 3, lc = (c & 7) * 8;
    u16x8 o;
    #pragma unroll
    for (int e = 0; e < 8; e++) o[e] = T[(lc + e) * 65 + d];
    *(u16x8*)(Vt + (size_t)((b*16 + h) * 128 + d0 + d) * 2048 + l0 + lc) = o;
  }
}

// ---------------------------------------------------------------- attn staging helpers
static __device__ __forceinline__ void stage_k_tile(
    const u16* __restrict__ QKV, int b, int h, int j0, u16* Kbuf, int tid, int wid)
{
  #pragma unroll
  for (int i = 0; i < 4; i++) {
    int c = i * 256 + tid;
    int r = c >> 4, ob = (c & 15) * 16;
    int cb = ob ^ ((r & 7) << 4);
    const u16* g = QKV + (size_t)(b*2048 + j0 + r) * 6144 + 2048 + h*128 + (cb >> 1);
    gload_lds16(g, Kbuf + (i * 256 + wid * 64) * 8);
  }
}
static __device__ __forceinline__ void stage_v_tile(
    const u16* __restrict__ Vt, int b, int h, int j0, u16* Vbuf, int tid, int wid)
{
  #pragma unroll
  for (int i = 0; i < 4; i++) {
    int c = i * 256 + tid;
    int r = c >> 3, ob = (c & 7) * 16;
    int cb = ob ^ ((r & 7) << 4);
    const u16* g = Vt + (size_t)((b*16 + h) * 128 + r) * 2048 + j0 + (cb >> 1);
    gload_lds16(g, Vbuf + (i * 256 + wid * 64) * 8);
  }
}

// ---------------------------------------------------------------- causal flash attention
// Pairing (pair, 31-pair) for balance. K AND V double-buffered (vmcnt(8)).
// XCD swizzle: each XCD owns 4 heads x 1 batch (K+V = 4MB = one L2).
// Defer-max (THR=8 log2), deferred lrun reduction, truncating P->bf16.
__global__ __launch_bounds__(256) void attn(
    const u16* __restrict__ QKV, const u16* __restrict__ Vt, u16* __restrict__ AO)
{
  const int flat = blockIdx.x + (blockIdx.y << 4) + (blockIdx.z << 8);  // 0..511
  const int swz = (flat & 7) * 64 + (flat >> 3);
  const int pair = swz & 15;
  const int h = (swz >> 4) & 15;
  const int b = swz >> 8;
  const int tid = threadIdx.x, lane = tid & 63, wid = tid >> 6;

  __shared__ u16 Ks[2][64 * 128];
  __shared__ u16 Vs[2][128 * 64];
  __shared__ u16 Ps[4][16 * 64];

  for (int side = 0; side < 2; side++) {
    const int pp = side ? (31 - pair) : pair;
    const int l0 = pp * 64;
    const int ntile = pp + 1;

    bf16x8 qa[4];
    const u16* qrow = QKV + (size_t)(b*2048 + l0 + wid*16 + (lane & 15)) * 6144
                      + h*128 + (lane >> 4) * 8;
    #pragma unroll
    for (int ks = 0; ks < 4; ks++) qa[ks] = *(const bf16x8*)(qrow + ks * 32);

    f32x4 o[8] = {};
    float mrun[4] = {-1e30f, -1e30f, -1e30f, -1e30f};
    float lrun[4] = {};

    stage_v_tile(Vt, b, h, 0, Vs[0], tid, wid);
    stage_k_tile(QKV, b, h, 0, Ks[0], tid, wid);
    int cur = 0;

    for (int t = 0; t < ntile; t++) {
      if (t + 1 < ntile) {
        stage_v_tile(Vt, b, h, (t + 1) * 64, Vs[cur ^ 1], tid, wid);
        stage_k_tile(QKV, b, h, (t + 1) * 64, Ks[cur ^ 1], tid, wid);
        asm volatile("s_waitcnt vmcnt(8)" ::: "memory");   // wait K(t),V(t); next 8 fly
      } else {
        asm volatile("s_waitcnt vmcnt(0)" ::: "memory");
      }
      __builtin_amdgcn_s_barrier();
      asm volatile("" ::: "memory");

      // ---- S = Q K^T (already in log2 domain: Q pre-scaled in ln_qk)
      f32x4 s[4] = {};
      const char* Kc = (const char*)Ks[cur];
      __builtin_amdgcn_s_setprio(1);
      #pragma unroll
      for (int nt = 0; nt < 4; nt++) {
        #pragma unroll
        for (int ks = 0; ks < 4; ks++) {
          int r = nt * 16 + (lane & 15);
          int cb = ks * 64 + (lane >> 4) * 16;
          bf16x8 kb = *(const bf16x8*)(Kc + r * 256 + (cb ^ ((lane & 7) << 4)));
          s[nt] = __builtin_amdgcn_mfma_f32_16x16x32_bf16(qa[ks], kb, s[nt], 0, 0, 0);
        }
      }
      __builtin_amdgcn_s_setprio(0);

      // ---- causal mask (diagonal tile only)
      if (t == ntile - 1) {
        #pragma unroll
        for (int nt = 0; nt < 4; nt++) {
          #pragma unroll
          for (int e = 0; e < 4; e++) {
            int i_loc = wid * 16 + (lane >> 4) * 4 + e;
            int j_loc = nt * 16 + (lane & 15);
            if (j_loc > i_loc) s[nt][e] = -1e30f;
          }
        }
      }

      // ---- group max (4 shfl per row-slot)
      float pmax[4];
      #pragma unroll
      for (int e = 0; e < 4; e++) {
        float v = fmaxf(fmaxf(s[0][e], s[1][e]), fmaxf(s[2][e], s[3][e]));
        v = fmaxf(v, __shfl_xor(v, 1));
        v = fmaxf(v, __shfl_xor(v, 2));
        v = fmaxf(v, __shfl_xor(v, 4));
        v = fmaxf(v, __shfl_xor(v, 8));
        pmax[e] = v;
      }
      // ---- defer-max: rescale only when some row's max grew by > 8 (log2)
      bool need = (pmax[0] > mrun[0] + 8.f) || (pmax[1] > mrun[1] + 8.f) ||
                  (pmax[2] > mrun[2] + 8.f) || (pmax[3] > mrun[3] + 8.f);
      if (__any(need)) {
        float alpha[4];
        #pragma unroll
        for (int e = 0; e < 4; e++) {
          float mi = fmaxf(mrun[e], pmax[e]);
          alpha[e] = exp2f(mrun[e] - mi);
          mrun[e] = mi;
          lrun[e] *= alpha[e];
        }
        #pragma unroll
        for (int dt = 0; dt < 8; dt++)
          #pragma unroll
          for (int e = 0; e < 4; e++)
            o[dt][e] *= alpha[e];
      }

      // ---- P = exp2(S - m); per-lane partial row-sum (reduced at epilogue)
      char* PsW = (char*)Ps[wid];
      #pragma unroll
      for (int nt = 0; nt < 4; nt++) {
        #pragma unroll
        for (int e = 0; e < 4; e++) {
          float p = exp2f(s[nt][e] - mrun[e]);
          lrun[e] += p;
          int i_ = (lane >> 4) * 4 + e;
          int jb = (nt * 16 + (lane & 15)) * 2;
          *(u16*)(PsW + i_ * 128 + (jb ^ ((i_ & 7) << 4))) = f2bf_trunc(p);
        }
      }

      // ---- O += P V
      const char* Vc = (const char*)Vs[cur];
      __builtin_amdgcn_s_setprio(1);
      #pragma unroll
      for (int ks = 0; ks < 2; ks++) {
        int ir = lane & 15;
        int jb = ks * 64 + (lane >> 4) * 16;
        bf16x8 pa = *(const bf16x8*)(PsW + ir * 128 + (jb ^ ((ir & 7) << 4)));
        #pragma unroll
        for (int dt = 0; dt < 8; dt++) {
          int dr = dt * 16 + (lane & 15);
          bf16x8 vb = *(const bf16x8*)(Vc + dr * 128 + (jb ^ ((lane & 7) << 4)));
          o[dt] = __builtin_amdgcn_mfma_f32_16x16x32_bf16(pa, vb, o[dt], 0, 0, 0);
        }
      }
      __builtin_amdgcn_s_setprio(0);

      asm volatile("s_waitcnt lgkmcnt(0)" ::: "memory");
      __builtin_amdgcn_s_barrier();
      asm volatile("" ::: "memory");
      cur ^= 1;
    }

    // ---- epilogue: finish deferred lrun reduction, normalize, store
    #pragma unroll
    for (int e = 0; e < 4; e++) {
      float l = lrun[e];
      l += __shfl_xor(l, 1);
      l += __shfl_xor(l, 2);
      l += __shfl_xor(l, 4);
      l += __shfl_xor(l, 8);
      float inv = 1.0f / l;
      int rglob = b * 2048 + l0 + wid * 16 + (lane >> 4) * 4 + e;
      #pragma unroll
      for (int dt = 0; dt < 8; dt++)
        AO[(size_t)rglob * 2048 + h * 128 + dt * 16 + (lane & 15)] = f2bf(o[dt][e] * inv);
    }
  }
}

// ---------------------------------------------------------------- launch
extern "C" void kernel_launch(void* const* d_in, const int* in_sizes, int n_in,
                              void* d_out, int out_size, void* d_ws, size_t ws_size,
                              hipStream_t stream)
{
  const float* x  = (const float*)d_in[0];
  const float* Wq = (const float*)d_in[1];
  const float* Wk = (const float*)d_in[2];
  const float* Wv = (const float*)d_in[3];
  const float* Wo = (const float*)d_in[4];
  const float* bo = (const float*)d_in[5];

  char* ws = (char*)d_ws;
  u16* xb   = (u16*)(ws);
  u16* Wcat = (u16*)(ws + 16777216);
  u16* Wob  = (u16*)(ws + 16777216 + 25165824);
  u16* QKV  = (u16*)(ws + 16777216 + 25165824 + 8388608);
  u16* AO   = xb;
  u16* Vt   = Wcat;

  cast_all<<<dim3(2048), dim3(256), 0, stream>>>(x, Wq, Wk, Wv, Wo, xb, Wcat, Wob);
  gemm256<<<dim3(32, 16), dim3(512), 0, stream>>>(xb, Wcat, QKV, 4096, 6144, 2048);
  ln_qk<<<dim3(4096), dim3(256), 0, stream>>>(QKV);
  transpose_v<<<dim3(2, 32, 32), dim3(256), 0, stream>>>(QKV, Vt);
  attn<<<dim3(16, 16, 2), dim3(256), 0, stream>>>(QKV, Vt, AO);
  gemm_nt<true><<<dim3(16, 32), dim3(256), 0, stream>>>(AO, Wob, d_out, bo, 4096, 2048, 2048);
}

// Round 6
// 279.863 us; speedup vs baseline: 1.7944x; 1.0544x over previous
//
#include <hip/hip_runtime.h>
#include <stdint.h>

typedef unsigned short u16;
typedef __attribute__((ext_vector_type(8))) unsigned short u16x8;
typedef __attribute__((ext_vector_type(8))) __bf16 bf16x8;
typedef __attribute__((ext_vector_type(4))) float f32x4;
typedef __attribute__((ext_vector_type(8))) float f32x8;

#define AS_G __attribute__((address_space(1)))
#define AS_L __attribute__((address_space(3)))

static __device__ __forceinline__ void gload_lds16(const u16* g, u16* l) {
  __builtin_amdgcn_global_load_lds((AS_G void*)(u16*)g, (AS_L void*)l, 16, 0, 0);
}

static __device__ __forceinline__ u16 f2bf(float f) {
  union { float f; unsigned u; } v; v.f = f;
  return (u16)((v.u + 0x7FFFu + ((v.u >> 16) & 1u)) >> 16);
}
static __device__ __forceinline__ float bf2f(u16 b) {
  union { unsigned u; float f; } v; v.u = ((unsigned)b) << 16;
  return v.f;
}
static __device__ __forceinline__ u16 f2bf_trunc(float f) {
  union { float f; unsigned u; } v; v.f = f;
  return (u16)(v.u >> 16);
}

#define BAR() do { asm volatile("" ::: "memory"); __builtin_amdgcn_s_barrier(); asm volatile("" ::: "memory"); } while (0)

// ---------------------------------------------------------------- cast fp32->bf16
__global__ __launch_bounds__(256) void cast_all(
    const float* __restrict__ x, const float* __restrict__ Wq,
    const float* __restrict__ Wk, const float* __restrict__ Wv,
    const float* __restrict__ Wo,
    u16* __restrict__ xb, u16* __restrict__ Wcat, u16* __restrict__ Wob)
{
  const int NX = (4096 * 2048) / 8;
  const int NW = (2048 * 2048) / 8;
  const int total = NX + 4 * NW;
  for (int i = blockIdx.x * 256 + threadIdx.x; i < total; i += gridDim.x * 256) {
    const float* src; u16* dst; int idx;
    if (i < NX)               { src = x;  dst = xb;                 idx = i; }
    else if (i < NX + NW)     { src = Wq; dst = Wcat;               idx = i - NX; }
    else if (i < NX + 2*NW)   { src = Wk; dst = Wcat + 2048*2048;   idx = i - NX - NW; }
    else if (i < NX + 3*NW)   { src = Wv; dst = Wcat + 2*2048*2048; idx = i - NX - 2*NW; }
    else                      { src = Wo; dst = Wob;                idx = i - NX - 3*NW; }
    f32x8 v = *(const f32x8*)(src + (size_t)idx * 8);
    u16x8 o;
    #pragma unroll
    for (int e = 0; e < 8; e++) o[e] = f2bf(v[e]);
    *(u16x8*)(dst + (size_t)idx * 8) = o;
  }
}

// ---------------------------------------------------------------- 256^2 8-phase NT GEMM + fused per-head LN
// C[i][j] = sum_k A[i][k]*B[j][k]. BM=BN=256, BK=64, 512 thr (8 waves 2Mx4N).
// R3-proven schedule (116us): 4 phases/K-tile, stage A0/A1/B0/B1 halves,
// vmcnt(4) only at phase boundaries of the staging pipeline.
// Epilogue fuses per-head (128-col) LayerNorm for Q/K col-tiles and the
// 1/sqrt(128)*log2(e) Q-scale. BN=256 = exactly 2 heads; partner wave = wid^1.
#define MFMA2(q, x00, x01, x10, x11) \
  do { __builtin_amdgcn_s_setprio(1); \
    _Pragma("unroll") \
    for (int nf = 0; nf < 4; ++nf) { \
      acc[2*(q)][nf]   = __builtin_amdgcn_mfma_f32_16x16x32_bf16(x00, breg[nf][0], acc[2*(q)][nf], 0, 0, 0); \
      acc[2*(q)][nf]   = __builtin_amdgcn_mfma_f32_16x16x32_bf16(x01, breg[nf][1], acc[2*(q)][nf], 0, 0, 0); \
      acc[2*(q)+1][nf] = __builtin_amdgcn_mfma_f32_16x16x32_bf16(x10, breg[nf][0], acc[2*(q)+1][nf], 0, 0, 0); \
      acc[2*(q)+1][nf] = __builtin_amdgcn_mfma_f32_16x16x32_bf16(x11, breg[nf][1], acc[2*(q)+1][nf], 0, 0, 0); \
    } \
    __builtin_amdgcn_s_setprio(0); } while (0)

__global__ __launch_bounds__(512, 2) void gemm256(
    const u16* __restrict__ A, const u16* __restrict__ B,
    u16* __restrict__ Cout, int M, int N, int K)
{
  __shared__ u16 As[2][256 * 64];
  __shared__ u16 Bs[2][256 * 64];
  const int tid = threadIdx.x, lane = tid & 63, wid = tid >> 6;
  const int wm = wid >> 2, wn = wid & 3;
  const int row0 = blockIdx.y * 256, col0 = blockIdx.x * 256;
  const int NT = K >> 6;

  const int sr  = tid >> 3;
  const int scb = ((tid & 7) * 16) ^ ((sr & 7) << 4);

  auto stA = [&](int buf, int t, int half) {
    const u16* src = A + (size_t)(row0 + half * 128 + sr) * K + t * 64 + (scb >> 1);
    u16* dst = As[buf] + half * 8192 + wid * 512;
    gload_lds16(src, dst);
    gload_lds16(src + (size_t)64 * K, dst + 4096);
  };
  auto stB = [&](int buf, int t, int half) {
    const u16* src = B + (size_t)(col0 + half * 128 + sr) * K + t * 64 + (scb >> 1);
    u16* dst = Bs[buf] + half * 8192 + wid * 512;
    gload_lds16(src, dst);
    gload_lds16(src + (size_t)64 * K, dst + 4096);
  };
  auto ldA = [&](int buf, int mf, int k) {
    int ra = wm * 128 + mf * 16 + (lane & 15);
    int bc = (k * 64 + ((lane >> 4) << 4)) ^ ((ra & 7) << 4);
    return *(const bf16x8*)((const char*)As[buf] + ra * 128 + bc);
  };
  auto ldB = [&](int buf, int nf, int k) {
    int rb = wn * 64 + nf * 16 + (lane & 15);
    int bc = (k * 64 + ((lane >> 4) << 4)) ^ ((rb & 7) << 4);
    return *(const bf16x8*)((const char*)Bs[buf] + rb * 128 + bc);
  };

  f32x4 acc[8][4] = {};
  bf16x8 breg[4][2];

  stA(0, 0, 0); stA(0, 0, 1); stB(0, 0, 0); stB(0, 0, 1);
  stB(1, 1, 0); stB(1, 1, 1);
  asm volatile("s_waitcnt vmcnt(4)" ::: "memory");
  BAR();

  for (int it = 0; it < NT / 2; ++it) {
    const int t1  = 2 * it + 1;
    const int pf0 = (2 * it + 2 < NT) ? (2 * it + 2) : (NT - 1);
    const int pf1 = (2 * it + 3 < NT) ? (2 * it + 3) : (NT - 1);
    #pragma unroll
    for (int hf = 0; hf < 2; ++hf) {
      const int cb = hf;
      #pragma unroll
      for (int nf = 0; nf < 4; ++nf) {
        breg[nf][0] = ldB(cb, nf, 0);
        breg[nf][1] = ldB(cb, nf, 1);
      }
      bf16x8 a00 = ldA(cb, 0, 0), a01 = ldA(cb, 0, 1);
      bf16x8 a10 = ldA(cb, 1, 0), a11 = ldA(cb, 1, 1);
      BAR();
      if (hf == 0) stA(1, t1, 0); else stA(0, pf0, 0);
      MFMA2(0, a00, a01, a10, a11);
      a00 = ldA(cb, 2, 0); a01 = ldA(cb, 2, 1);
      a10 = ldA(cb, 3, 0); a11 = ldA(cb, 3, 1);
      BAR();
      if (hf == 0) stA(1, t1, 1); else stA(0, pf0, 1);
      MFMA2(1, a00, a01, a10, a11);
      a00 = ldA(cb, 4, 0); a01 = ldA(cb, 4, 1);
      a10 = ldA(cb, 5, 0); a11 = ldA(cb, 5, 1);
      BAR();
      if (hf == 0) stB(0, pf0, 0); else stB(1, pf1, 0);
      MFMA2(2, a00, a01, a10, a11);
      a00 = ldA(cb, 6, 0); a01 = ldA(cb, 6, 1);
      a10 = ldA(cb, 7, 0); a11 = ldA(cb, 7, 1);
      BAR();
      if (hf == 0) stB(0, pf0, 1); else stB(1, pf1, 1);
      MFMA2(3, a00, a01, a10, a11);
      asm volatile("s_waitcnt vmcnt(4)" ::: "memory");
      BAR();
    }
  }
  asm volatile("s_waitcnt vmcnt(0)" ::: "memory");
  BAR();   // all gload_lds drained; LDS now reusable as reduction scratch

  if (col0 < 4096) {
    // ---- fused per-head LayerNorm (+ Q pre-scale). Head = 128 cols = wave pair (wid, wid^1).
    float* red = (float*)As;   // [8 waves][128 rows][2] = 8 KB
    #pragma unroll
    for (int mf = 0; mf < 8; ++mf) {
      #pragma unroll
      for (int e = 0; e < 4; ++e) {
        float s = acc[mf][0][e] + acc[mf][1][e] + acc[mf][2][e] + acc[mf][3][e];
        float q = acc[mf][0][e]*acc[mf][0][e] + acc[mf][1][e]*acc[mf][1][e]
                + acc[mf][2][e]*acc[mf][2][e] + acc[mf][3][e]*acc[mf][3][e];
        #pragma unroll
        for (int m = 1; m < 16; m <<= 1) { s += __shfl_xor(s, m); q += __shfl_xor(q, m); }
        if ((lane & 15) == 0) {
          int rl = mf * 16 + (lane >> 4) * 4 + e;
          red[wid * 256 + rl * 2]     = s;
          red[wid * 256 + rl * 2 + 1] = q;
        }
      }
    }
    BAR();
    const float mul = (col0 < 2048) ? (0.08838834764831845f * 1.4426950408889634f) : 1.0f;
    #pragma unroll
    for (int mf = 0; mf < 8; ++mf) {
      #pragma unroll
      for (int e = 0; e < 4; ++e) {
        int rl = mf * 16 + (lane >> 4) * 4 + e;
        float s = red[wid * 256 + rl * 2]     + red[(wid ^ 1) * 256 + rl * 2];
        float q = red[wid * 256 + rl * 2 + 1] + red[(wid ^ 1) * 256 + rl * 2 + 1];
        float mu = s * (1.f / 128.f);
        float var = q * (1.f / 128.f) - mu * mu;
        float rstd = rsqrtf(var + 1e-5f) * mul;
        int r = row0 + wm * 128 + rl;
        #pragma unroll
        for (int nf = 0; nf < 4; ++nf) {
          int c = col0 + wn * 64 + nf * 16 + (lane & 15);
          Cout[(size_t)r * N + c] = f2bf((acc[mf][nf][e] - mu) * rstd);
        }
      }
    }
  } else {
    // ---- V col-tiles: plain store
    #pragma unroll
    for (int mf = 0; mf < 8; ++mf) {
      #pragma unroll
      for (int nf = 0; nf < 4; ++nf) {
        #pragma unroll
        for (int e = 0; e < 4; ++e) {
          int r = row0 + wm * 128 + mf * 16 + (lane >> 4) * 4 + e;
          int c = col0 + wn * 64 + nf * 16 + (lane & 15);
          Cout[(size_t)r * N + c] = f2bf(acc[mf][nf][e]);
        }
      }
    }
  }
}

// ---------------------------------------------------------------- AO @ Wo^T + bias (8-phase, 1-round grid)
// BM=256, BN=128, BK=64, 512 thr (8 waves 4Mx2N, per-wave 64x64).
// Grid (16,16) = 256 blocks = exactly 1 round of 256 CUs.
// 3 phases/K-tile (MFMA 8/16/8); counted vmcnt(2); retirement verified:
// B-stage 2 barriers after B-read; A-stages target the non-read buffer.
__global__ __launch_bounds__(512, 2) void gemm_ao(
    const u16* __restrict__ A, const u16* __restrict__ B,
    float* __restrict__ C, const float* __restrict__ bias,
    int M, int N, int K)
{
  __shared__ u16 As[2][256 * 64];   // 64 KB
  __shared__ u16 Bs[2][128 * 64];   // 32 KB
  const int tid = threadIdx.x, lane = tid & 63, wid = tid >> 6;
  const int wm = wid >> 1, wn = wid & 1;
  const int row0 = blockIdx.y * 256, col0 = blockIdx.x * 128;
  const int NT = K >> 6;

  const int sr  = tid >> 3;
  const int scb = ((tid & 7) * 16) ^ ((sr & 7) << 4);

  auto stA = [&](int buf, int t, int u) {
    const u16* src = A + (size_t)(row0 + u * 64 + sr) * K + t * 64 + (scb >> 1);
    gload_lds16(src, As[buf] + u * 4096 + wid * 512);
  };
  auto stB = [&](int buf, int t, int u) {
    const u16* src = B + (size_t)(col0 + u * 64 + sr) * K + t * 64 + (scb >> 1);
    gload_lds16(src, Bs[buf] + u * 4096 + wid * 512);
  };
  auto ldA = [&](int buf, int mf, int k) {
    int ra = wm * 64 + mf * 16 + (lane & 15);
    int bc = (k * 64 + ((lane >> 4) << 4)) ^ ((ra & 7) << 4);
    return *(const bf16x8*)((const char*)As[buf] + ra * 128 + bc);
  };
  auto ldB = [&](int buf, int nf, int k) {
    int rb = wn * 64 + nf * 16 + (lane & 15);
    int bc = (k * 64 + ((lane >> 4) << 4)) ^ ((rb & 7) << 4);
    return *(const bf16x8*)((const char*)Bs[buf] + rb * 128 + bc);
  };

  f32x4 acc[4][4] = {};
  bf16x8 breg[4][2];

  // prologue: tile0 A+B -> buf0; B(tile1) -> buf1
  stA(0, 0, 0); stA(0, 0, 1); stA(0, 0, 2); stA(0, 0, 3);
  stB(0, 0, 0); stB(0, 0, 1);
  stB(1, 1, 0); stB(1, 1, 1);
  asm volatile("s_waitcnt vmcnt(2)" ::: "memory");
  BAR();

  for (int it = 0; it < NT / 2; ++it) {
    const int t1  = 2 * it + 1;
    const int pf0 = (2 * it + 2 < NT) ? (2 * it + 2) : (NT - 1);
    const int pf1 = (2 * it + 3 < NT) ? (2 * it + 3) : (NT - 1);
    #pragma unroll
    for (int hf = 0; hf < 2; ++hf) {
      const int cb = hf;
      // ---- phase 0: read all B + A mf0 ; stage A(next) u0,u1 ; 8 MFMA
      #pragma unroll
      for (int nf = 0; nf < 4; ++nf) { breg[nf][0] = ldB(cb, nf, 0); breg[nf][1] = ldB(cb, nf, 1); }
      bf16x8 a0 = ldA(cb, 0, 0), a1 = ldA(cb, 0, 1);
      BAR();
      if (hf == 0) { stA(1, t1, 0); stA(1, t1, 1); } else { stA(0, pf0, 0); stA(0, pf0, 1); }
      __builtin_amdgcn_s_setprio(1);
      #pragma unroll
      for (int nf = 0; nf < 4; ++nf) {
        acc[0][nf] = __builtin_amdgcn_mfma_f32_16x16x32_bf16(a0, breg[nf][0], acc[0][nf], 0, 0, 0);
        acc[0][nf] = __builtin_amdgcn_mfma_f32_16x16x32_bf16(a1, breg[nf][1], acc[0][nf], 0, 0, 0);
      }
      __builtin_amdgcn_s_setprio(0);
      // ---- phase 1: read A mf1,mf2 ; stage A(next) u2,u3 ; 16 MFMA
      bf16x8 b0 = ldA(cb, 1, 0), b1 = ldA(cb, 1, 1);
      bf16x8 c0 = ldA(cb, 2, 0), c1 = ldA(cb, 2, 1);
      BAR();
      if (hf == 0) { stA(1, t1, 2); stA(1, t1, 3); } else { stA(0, pf0, 2); stA(0, pf0, 3); }
      __builtin_amdgcn_s_setprio(1);
      #pragma unroll
      for (int nf = 0; nf < 4; ++nf) {
        acc[1][nf] = __builtin_amdgcn_mfma_f32_16x16x32_bf16(b0, breg[nf][0], acc[1][nf], 0, 0, 0);
        acc[1][nf] = __builtin_amdgcn_mfma_f32_16x16x32_bf16(b1, breg[nf][1], acc[1][nf], 0, 0, 0);
        acc[2][nf] = __builtin_amdgcn_mfma_f32_16x16x32_bf16(c0, breg[nf][0], acc[2][nf], 0, 0, 0);
        acc[2][nf] = __builtin_amdgcn_mfma_f32_16x16x32_bf16(c1, breg[nf][1], acc[2][nf], 0, 0, 0);
      }
      __builtin_amdgcn_s_setprio(0);
      // ---- phase 2: read A mf3 ; stage B(+2) u0,u1 ; 8 MFMA
      a0 = ldA(cb, 3, 0); a1 = ldA(cb, 3, 1);
      BAR();
      if (hf == 0) { stB(0, pf0, 0); stB(0, pf0, 1); } else { stB(1, pf1, 0); stB(1, pf1, 1); }
      __builtin_amdgcn_s_setprio(1);
      #pragma unroll
      for (int nf = 0; nf < 4; ++nf) {
        acc[3][nf] = __builtin_amdgcn_mfma_f32_16x16x32_bf16(a0, breg[nf][0], acc[3][nf], 0, 0, 0);
        acc[3][nf] = __builtin_amdgcn_mfma_f32_16x16x32_bf16(a1, breg[nf][1], acc[3][nf], 0, 0, 0);
      }
      __builtin_amdgcn_s_setprio(0);
      asm volatile("s_waitcnt vmcnt(2)" ::: "memory");
      BAR();
    }
  }
  asm volatile("s_waitcnt vmcnt(0)" ::: "memory");

  #pragma unroll
  for (int mf = 0; mf < 4; ++mf) {
    #pragma unroll
    for (int nf = 0; nf < 4; ++nf) {
      #pragma unroll
      for (int e = 0; e < 4; ++e) {
        int r = row0 + wm * 64 + mf * 16 + (lane >> 4) * 4 + e;
        int c = col0 + wn * 64 + nf * 16 + (lane & 15);
        C[(size_t)r * N + c] = acc[mf][nf][e] + bias[c];
      }
    }
  }
}

// ---------------------------------------------------------------- V -> Vt [b,h,d,l]
__global__ __launch_bounds__(256) void transpose_v(const u16* __restrict__ QKV, u16* __restrict__ Vt)
{
  __shared__ u16 T[64 * 65];
  const int d0 = blockIdx.x * 64;
  const int l0 = blockIdx.y * 64;
  const int bh = blockIdx.z;
  const int b = bh >> 4, h = bh & 15;
  const int t = threadIdx.x;
  #pragma unroll
  for (int i = 0; i < 2; i++) {
    int c = t + i * 256;
    int l = c >> 3, dc = (c & 7) * 8;
    u16x8 v = *(const u16x8*)(QKV + (size_t)(b*2048 + l0 + l) * 6144 + 4096 + h*128 + d0 + dc);
    #pragma unroll
    for (int e = 0; e < 8; e++) T[l * 65 + dc + e] = v[e];
  }
  __syncthreads();
  #pragma unroll
  for (int i = 0; i < 2; i++) {
    int c = t + i * 256;
    int d = c >> 3, lc = (c & 7) * 8;
    u16x8 o;
    #pragma unroll
    for (int e = 0; e < 8; e++) o[e] = T[(lc + e) * 65 + d];
    *(u16x8*)(Vt + (size_t)((b*16 + h) * 128 + d0 + d) * 2048 + l0 + lc) = o;
  }
}

// ---------------------------------------------------------------- attn staging helpers
static __device__ __forceinline__ void stage_k_tile(
    const u16* __restrict__ QKV, int b, int h, int j0, u16* Kbuf, int tid, int wid)
{
  #pragma unroll
  for (int i = 0; i < 4; i++) {
    int c = i * 256 + tid;
    int r = c >> 4, ob = (c & 15) * 16;
    int cb = ob ^ ((r & 7) << 4);
    const u16* g = QKV + (size_t)(b*2048 + j0 + r) * 6144 + 2048 + h*128 + (cb >> 1);
    gload_lds16(g, Kbuf + (i * 256 + wid * 64) * 8);
  }
}
static __device__ __forceinline__ void stage_v_tile(
    const u16* __restrict__ Vt, int b, int h, int j0, u16* Vbuf, int tid, int wid)
{
  #pragma unroll
  for (int i = 0; i < 4; i++) {
    int c = i * 256 + tid;
    int r = c >> 3, ob = (c & 7) * 16;
    int cb = ob ^ ((r & 7) << 4);
    const u16* g = Vt + (size_t)((b*16 + h) * 128 + r) * 2048 + j0 + (cb >> 1);
    gload_lds16(g, Vbuf + (i * 256 + wid * 64) * 8);
  }
}

// ---------------------------------------------------------------- causal flash attention
__global__ __launch_bounds__(256) void attn(
    const u16* __restrict__ QKV, const u16* __restrict__ Vt, u16* __restrict__ AO)
{
  const int flat = blockIdx.x + (blockIdx.y << 4) + (blockIdx.z << 8);
  const int swz = (flat & 7) * 64 + (flat >> 3);
  const int pair = swz & 15;
  const int h = (swz >> 4) & 15;
  const int b = swz >> 8;
  const int tid = threadIdx.x, lane = tid & 63, wid = tid >> 6;

  __shared__ u16 Ks[2][64 * 128];
  __shared__ u16 Vs[2][128 * 64];
  __shared__ u16 Ps[4][16 * 64];

  for (int side = 0; side < 2; side++) {
    const int pp = side ? (31 - pair) : pair;
    const int l0 = pp * 64;
    const int ntile = pp + 1;

    bf16x8 qa[4];
    const u16* qrow = QKV + (size_t)(b*2048 + l0 + wid*16 + (lane & 15)) * 6144
                      + h*128 + (lane >> 4) * 8;
    #pragma unroll
    for (int ks = 0; ks < 4; ks++) qa[ks] = *(const bf16x8*)(qrow + ks * 32);

    f32x4 o[8] = {};
    float mrun[4] = {-1e30f, -1e30f, -1e30f, -1e30f};
    float lrun[4] = {};

    stage_v_tile(Vt, b, h, 0, Vs[0], tid, wid);
    stage_k_tile(QKV, b, h, 0, Ks[0], tid, wid);
    int cur = 0;

    for (int t = 0; t < ntile; t++) {
      if (t + 1 < ntile) {
        stage_v_tile(Vt, b, h, (t + 1) * 64, Vs[cur ^ 1], tid, wid);
        stage_k_tile(QKV, b, h, (t + 1) * 64, Ks[cur ^ 1], tid, wid);
        asm volatile("s_waitcnt vmcnt(8)" ::: "memory");
      } else {
        asm volatile("s_waitcnt vmcnt(0)" ::: "memory");
      }
      __builtin_amdgcn_s_barrier();
      asm volatile("" ::: "memory");

      f32x4 s[4] = {};
      const char* Kc = (const char*)Ks[cur];
      __builtin_amdgcn_s_setprio(1);
      #pragma unroll
      for (int nt = 0; nt < 4; nt++) {
        #pragma unroll
        for (int ks = 0; ks < 4; ks++) {
          int r = nt * 16 + (lane & 15);
          int cb = ks * 64 + (lane >> 4) * 16;
          bf16x8 kb = *(const bf16x8*)(Kc + r * 256 + (cb ^ ((lane & 7) << 4)));
          s[nt] = __builtin_amdgcn_mfma_f32_16x16x32_bf16(qa[ks], kb, s[nt], 0, 0, 0);
        }
      }
      __builtin_amdgcn_s_setprio(0);

      if (t == ntile - 1) {
        #pragma unroll
        for (int nt = 0; nt < 4; nt++) {
          #pragma unroll
          for (int e = 0; e < 4; e++) {
            int i_loc = wid * 16 + (lane >> 4) * 4 + e;
            int j_loc = nt * 16 + (lane & 15);
            if (j_loc > i_loc) s[nt][e] = -1e30f;
          }
        }
      }

      float pmax[4];
      #pragma unroll
      for (int e = 0; e < 4; e++) {
        float v = fmaxf(fmaxf(s[0][e], s[1][e]), fmaxf(s[2][e], s[3][e]));
        v = fmaxf(v, __shfl_xor(v, 1));
        v = fmaxf(v, __shfl_xor(v, 2));
        v = fmaxf(v, __shfl_xor(v, 4));
        v = fmaxf(v, __shfl_xor(v, 8));
        pmax[e] = v;
      }
      bool need = (pmax[0] > mrun[0] + 8.f) || (pmax[1] > mrun[1] + 8.f) ||
                  (pmax[2] > mrun[2] + 8.f) || (pmax[3] > mrun[3] + 8.f);
      if (__any(need)) {
        float alpha[4];
        #pragma unroll
        for (int e = 0; e < 4; e++) {
          float mi = fmaxf(mrun[e], pmax[e]);
          alpha[e] = exp2f(mrun[e] - mi);
          mrun[e] = mi;
          lrun[e] *= alpha[e];
        }
        #pragma unroll
        for (int dt = 0; dt < 8; dt++)
          #pragma unroll
          for (int e = 0; e < 4; e++)
            o[dt][e] *= alpha[e];
      }

      char* PsW = (char*)Ps[wid];
      #pragma unroll
      for (int nt = 0; nt < 4; nt++) {
        #pragma unroll
        for (int e = 0; e < 4; e++) {
          float p = exp2f(s[nt][e] - mrun[e]);
          lrun[e] += p;
          int i_ = (lane >> 4) * 4 + e;
          int jb = (nt * 16 + (lane & 15)) * 2;
          *(u16*)(PsW + i_ * 128 + (jb ^ ((i_ & 7) << 4))) = f2bf_trunc(p);
        }
      }

      const char* Vc = (const char*)Vs[cur];
      __builtin_amdgcn_s_setprio(1);
      #pragma unroll
      for (int ks = 0; ks < 2; ks++) {
        int ir = lane & 15;
        int jb = ks * 64 + (lane >> 4) * 16;
        bf16x8 pa = *(const bf16x8*)(PsW + ir * 128 + (jb ^ ((ir & 7) << 4)));
        #pragma unroll
        for (int dt = 0; dt < 8; dt++) {
          int dr = dt * 16 + (lane & 15);
          bf16x8 vb = *(const bf16x8*)(Vc + dr * 128 + (jb ^ ((lane & 7) << 4)));
          o[dt] = __builtin_amdgcn_mfma_f32_16x16x32_bf16(pa, vb, o[dt], 0, 0, 0);
        }
      }
      __builtin_amdgcn_s_setprio(0);

      asm volatile("s_waitcnt lgkmcnt(0)" ::: "memory");
      __builtin_amdgcn_s_barrier();
      asm volatile("" ::: "memory");
      cur ^= 1;
    }

    #pragma unroll
    for (int e = 0; e < 4; e++) {
      float l = lrun[e];
      l += __shfl_xor(l, 1);
      l += __shfl_xor(l, 2);
      l += __shfl_xor(l, 4);
      l += __shfl_xor(l, 8);
      float inv = 1.0f / l;
      int rglob = b * 2048 + l0 + wid * 16 + (lane >> 4) * 4 + e;
      #pragma unroll
      for (int dt = 0; dt < 8; dt++)
        AO[(size_t)rglob * 2048 + h * 128 + dt * 16 + (lane & 15)] = f2bf(o[dt][e] * inv);
    }
  }
}

// ---------------------------------------------------------------- launch
extern "C" void kernel_launch(void* const* d_in, const int* in_sizes, int n_in,
                              void* d_out, int out_size, void* d_ws, size_t ws_size,
                              hipStream_t stream)
{
  const float* x  = (const float*)d_in[0];
  const float* Wq = (const float*)d_in[1];
  const float* Wk = (const float*)d_in[2];
  const float* Wv = (const float*)d_in[3];
  const float* Wo = (const float*)d_in[4];
  const float* bo = (const float*)d_in[5];

  char* ws = (char*)d_ws;
  u16* xb   = (u16*)(ws);
  u16* Wcat = (u16*)(ws + 16777216);
  u16* Wob  = (u16*)(ws + 16777216 + 25165824);
  u16* QKV  = (u16*)(ws + 16777216 + 25165824 + 8388608);
  u16* AO   = xb;
  u16* Vt   = Wcat;

  cast_all<<<dim3(2048), dim3(256), 0, stream>>>(x, Wq, Wk, Wv, Wo, xb, Wcat, Wob);
  gemm256<<<dim3(24, 16), dim3(512), 0, stream>>>(xb, Wcat, QKV, 4096, 6144, 2048);
  transpose_v<<<dim3(2, 32, 32), dim3(256), 0, stream>>>(QKV, Vt);
  attn<<<dim3(16, 16, 2), dim3(256), 0, stream>>>(QKV, Vt, AO);
  gemm_ao<<<dim3(16, 16), dim3(512), 0, stream>>>(AO, Wob, (float*)d_out, bo, 4096, 2048, 2048);
}

// Round 7
// 258.884 us; speedup vs baseline: 1.9398x; 1.0810x over previous
//
#include <hip/hip_runtime.h>
#include <stdint.h>

typedef unsigned short u16;
typedef __attribute__((ext_vector_type(8))) unsigned short u16x8;
typedef __attribute__((ext_vector_type(8))) __bf16 bf16x8;
typedef __attribute__((ext_vector_type(4))) float f32x4;
typedef __attribute__((ext_vector_type(8))) float f32x8;

#define AS_G __attribute__((address_space(1)))
#define AS_L __attribute__((address_space(3)))

static __device__ __forceinline__ void gload_lds16(const u16* g, u16* l) {
  __builtin_amdgcn_global_load_lds((AS_G void*)(u16*)g, (AS_L void*)l, 16, 0, 0);
}

static __device__ __forceinline__ u16 f2bf(float f) {
  union { float f; unsigned u; } v; v.f = f;
  return (u16)((v.u + 0x7FFFu + ((v.u >> 16) & 1u)) >> 16);
}
static __device__ __forceinline__ float bf2f(u16 b) {
  union { unsigned u; float f; } v; v.u = ((unsigned)b) << 16;
  return v.f;
}
static __device__ __forceinline__ u16 f2bf_trunc(float f) {
  union { float f; unsigned u; } v; v.f = f;
  return (u16)(v.u >> 16);
}

#define BAR() do { asm volatile("" ::: "memory"); __builtin_amdgcn_s_barrier(); asm volatile("" ::: "memory"); } while (0)

// ---------------------------------------------------------------- cast fp32->bf16
__global__ __launch_bounds__(256) void cast_all(
    const float* __restrict__ x, const float* __restrict__ Wq,
    const float* __restrict__ Wk, const float* __restrict__ Wv,
    const float* __restrict__ Wo,
    u16* __restrict__ xb, u16* __restrict__ Wcat, u16* __restrict__ Wob)
{
  const int NX = (4096 * 2048) / 8;
  const int NW = (2048 * 2048) / 8;
  const int total = NX + 4 * NW;
  for (int i = blockIdx.x * 256 + threadIdx.x; i < total; i += gridDim.x * 256) {
    const float* src; u16* dst; int idx;
    if (i < NX)               { src = x;  dst = xb;                 idx = i; }
    else if (i < NX + NW)     { src = Wq; dst = Wcat;               idx = i - NX; }
    else if (i < NX + 2*NW)   { src = Wk; dst = Wcat + 2048*2048;   idx = i - NX - NW; }
    else if (i < NX + 3*NW)   { src = Wv; dst = Wcat + 2*2048*2048; idx = i - NX - 2*NW; }
    else                      { src = Wo; dst = Wob;                idx = i - NX - 3*NW; }
    f32x8 v = *(const f32x8*)(src + (size_t)idx * 8);
    u16x8 o;
    #pragma unroll
    for (int e = 0; e < 8; e++) o[e] = f2bf(v[e]);
    *(u16x8*)(dst + (size_t)idx * 8) = o;
  }
}

// ---------------------------------------------------------------- QKV GEMM: BM=128 x BN=256, 8-phase
// C[i][j] = sum_k A[i][k]*B[j][k]; A=xb [4096][2048], B=Wcat [6144][2048].
// Grid (32,24) = 768 blocks = EXACTLY 3 rounds of 256 CUs (perfect balance).
// 512 thr = 8 waves (2M x 4N), per-wave 64x64, acc = 64 VGPR (no LN spill).
// LDS 96 KB aliased: A dbuf 32K + B dbuf 64K; epilogue reuses for LN red / V transpose.
// Per K-tile: ph0 {read 8 B-frags + A-mf0; stage A(next) u0,u1}, ph1 {A-mf1;
// stage B(+2) u0,u1}, ph2 {A-mf2; stage B(+2) u2,u3}, ph3 {A-mf3; vmcnt(4)}.
// Retirement: B(buf) fully read in ph0 (barrier before ph1 stage); A(buf) last
// read ph3, staged next hf after barrier. vmcnt(4) = keep 4 newest (B of t+2).
// Epilogue: QK panels (col0<4096): fused per-head LN (+ Q*1/sqrt(128)*log2e);
// V panels: in-LDS transpose -> Vt[b,h,d,l] direct (kills transpose_v kernel).
__global__ __launch_bounds__(512, 1) void gemm_qkv(
    const u16* __restrict__ A, const u16* __restrict__ B,
    u16* __restrict__ QK, u16* __restrict__ Vt, int K)
{
  __shared__ char SM[98304];
  u16* Asb = (u16*)SM;              // 2 x 128x64 x 2B = 32 KB
  u16* Bsb = (u16*)(SM + 32768);    // 2 x 256x64 x 2B = 64 KB
  const int tid = threadIdx.x, lane = tid & 63, wid = tid >> 6;
  const int wm = wid >> 2, wn = wid & 3;
  const int row0 = blockIdx.x * 128, col0 = blockIdx.y * 256;
  const int NT = K >> 6;   // 32

  const int sr  = tid >> 3;
  const int scb = ((tid & 7) * 16) ^ ((sr & 7) << 4);

  auto stA = [&](int buf, int t, int u) {
    const u16* src = A + (size_t)(row0 + u * 64 + sr) * K + t * 64 + (scb >> 1);
    gload_lds16(src, Asb + buf * 8192 + u * 4096 + wid * 512);
  };
  auto stB = [&](int buf, int t, int u) {
    const u16* src = B + (size_t)(col0 + u * 64 + sr) * K + t * 64 + (scb >> 1);
    gload_lds16(src, Bsb + buf * 16384 + u * 4096 + wid * 512);
  };
  auto ldA = [&](int buf, int mf, int k) {
    int ra = wm * 64 + mf * 16 + (lane & 15);
    int bc = (k * 64 + ((lane >> 4) << 4)) ^ ((ra & 7) << 4);
    return *(const bf16x8*)((const char*)Asb + buf * 16384 + ra * 128 + bc);
  };
  auto ldB = [&](int buf, int nf, int k) {
    int rb = wn * 64 + nf * 16 + (lane & 15);
    int bc = (k * 64 + ((lane >> 4) << 4)) ^ ((rb & 7) << 4);
    return *(const bf16x8*)((const char*)Bsb + buf * 32768 + rb * 128 + bc);
  };

  f32x4 acc[4][4] = {};
  bf16x8 breg[4][2];

#define MFMA_PH(mf, x0, x1) \
  do { __builtin_amdgcn_s_setprio(1); \
    _Pragma("unroll") \
    for (int nf = 0; nf < 4; ++nf) { \
      acc[mf][nf] = __builtin_amdgcn_mfma_f32_16x16x32_bf16(x0, breg[nf][0], acc[mf][nf], 0, 0, 0); \
      acc[mf][nf] = __builtin_amdgcn_mfma_f32_16x16x32_bf16(x1, breg[nf][1], acc[mf][nf], 0, 0, 0); \
    } \
    __builtin_amdgcn_s_setprio(0); } while (0)

  // prologue: tile0 A+B -> buf0; B(tile1) -> buf1; leave B(t1) 4 in flight
  stA(0, 0, 0); stA(0, 0, 1);
  stB(0, 0, 0); stB(0, 0, 1); stB(0, 0, 2); stB(0, 0, 3);
  stB(1, 1, 0); stB(1, 1, 1); stB(1, 1, 2); stB(1, 1, 3);
  asm volatile("s_waitcnt vmcnt(4)" ::: "memory");
  BAR();

  for (int it = 0; it < NT / 2; ++it) {
    const int t1  = 2 * it + 1;
    const int pf0 = (2 * it + 2 < NT) ? (2 * it + 2) : (NT - 1);
    const int pf1 = (2 * it + 3 < NT) ? (2 * it + 3) : (NT - 1);
    #pragma unroll
    for (int hf = 0; hf < 2; ++hf) {
      const int cb = hf;
      // ph0: all B-frags + A mf0 ; stage A(next) u0,u1
      #pragma unroll
      for (int nf = 0; nf < 4; ++nf) { breg[nf][0] = ldB(cb, nf, 0); breg[nf][1] = ldB(cb, nf, 1); }
      bf16x8 a0 = ldA(cb, 0, 0), a1 = ldA(cb, 0, 1);
      BAR();
      if (hf == 0) { stA(1, t1, 0); stA(1, t1, 1); } else { stA(0, pf0, 0); stA(0, pf0, 1); }
      MFMA_PH(0, a0, a1);
      // ph1: A mf1 ; stage B(+2) u0,u1   [B(cb) fully read in ph0]
      a0 = ldA(cb, 1, 0); a1 = ldA(cb, 1, 1);
      BAR();
      if (hf == 0) { stB(0, pf0, 0); stB(0, pf0, 1); } else { stB(1, pf1, 0); stB(1, pf1, 1); }
      MFMA_PH(1, a0, a1);
      // ph2: A mf2 ; stage B(+2) u2,u3
      a0 = ldA(cb, 2, 0); a1 = ldA(cb, 2, 1);
      BAR();
      if (hf == 0) { stB(0, pf0, 2); stB(0, pf0, 3); } else { stB(1, pf1, 2); stB(1, pf1, 3); }
      MFMA_PH(2, a0, a1);
      // ph3: A mf3 ; counted wait (4 newest = B of t+2 stay in flight)
      a0 = ldA(cb, 3, 0); a1 = ldA(cb, 3, 1);
      MFMA_PH(3, a0, a1);
      asm volatile("s_waitcnt vmcnt(4)" ::: "memory");
      BAR();
    }
  }
  asm volatile("s_waitcnt vmcnt(0)" ::: "memory");
  BAR();   // all staging drained; LDS reusable

  if (col0 < 4096) {
    // ---- fused per-head LN (+ Q scale). Head = 128 cols = wave pair (wid, wid^1), same wm.
    float* red = (float*)SM;   // [8 waves][64 rows][2] = 4 KB
    #pragma unroll
    for (int mf = 0; mf < 4; ++mf) {
      #pragma unroll
      for (int e = 0; e < 4; ++e) {
        float s = acc[mf][0][e] + acc[mf][1][e] + acc[mf][2][e] + acc[mf][3][e];
        float q = acc[mf][0][e]*acc[mf][0][e] + acc[mf][1][e]*acc[mf][1][e]
                + acc[mf][2][e]*acc[mf][2][e] + acc[mf][3][e]*acc[mf][3][e];
        #pragma unroll
        for (int m = 1; m < 16; m <<= 1) { s += __shfl_xor(s, m); q += __shfl_xor(q, m); }
        if ((lane & 15) == 0) {
          int rl = mf * 16 + (lane >> 4) * 4 + e;
          red[wid * 128 + rl * 2]     = s;
          red[wid * 128 + rl * 2 + 1] = q;
        }
      }
    }
    BAR();
    const float mul = (col0 < 2048) ? (0.08838834764831845f * 1.4426950408889634f) : 1.0f;
    #pragma unroll
    for (int mf = 0; mf < 4; ++mf) {
      #pragma unroll
      for (int e = 0; e < 4; ++e) {
        int rl = mf * 16 + (lane >> 4) * 4 + e;
        float s = red[wid * 128 + rl * 2]     + red[(wid ^ 1) * 128 + rl * 2];
        float q = red[wid * 128 + rl * 2 + 1] + red[(wid ^ 1) * 128 + rl * 2 + 1];
        float mu = s * (1.f / 128.f);
        float var = q * (1.f / 128.f) - mu * mu;
        float rstd = rsqrtf(var + 1e-5f) * mul;
        int r = row0 + wm * 64 + rl;
        #pragma unroll
        for (int nf = 0; nf < 4; ++nf) {
          int c = col0 + wn * 64 + nf * 16 + (lane & 15);
          QK[(size_t)r * 4096 + c] = f2bf((acc[mf][nf][e] - mu) * rstd);
        }
      }
    }
  } else {
    // ---- V panels: in-LDS transpose (pad 136 keeps 16B-aligned rows) -> Vt[b,h,d,l]
    u16* T = (u16*)SM;     // 256 x 136 x 2B = 68 KB <= 96 KB
    #pragma unroll
    for (int mf = 0; mf < 4; ++mf) {
      #pragma unroll
      for (int nf = 0; nf < 4; ++nf) {
        #pragma unroll
        for (int e = 0; e < 4; ++e) {
          int r = wm * 64 + mf * 16 + (lane >> 4) * 4 + e;   // l within tile
          int c = wn * 64 + nf * 16 + (lane & 15);           // d within tile
          T[c * 136 + r] = f2bf(acc[mf][nf][e]);
        }
      }
    }
    BAR();
    const int dr = tid >> 1, half = tid & 1;
    const int dg = col0 - 4096 + dr;
    const int h = dg >> 7, dd = dg & 127;
    const int b = row0 >> 11;
    const int lb = (row0 & 2047) + half * 64;
    u16* dst = Vt + ((size_t)((b * 16 + h) * 128 + dd)) * 2048 + lb;
    const u16* srcT = T + dr * 136 + half * 64;
    #pragma unroll
    for (int j = 0; j < 8; ++j)
      *(u16x8*)(dst + j * 8) = *(const u16x8*)(srcT + j * 8);
  }
#undef MFMA_PH
}

// ---------------------------------------------------------------- AO @ Wo^T + bias (8-phase, 1-round grid)
__global__ __launch_bounds__(512, 2) void gemm_ao(
    const u16* __restrict__ A, const u16* __restrict__ B,
    float* __restrict__ C, const float* __restrict__ bias,
    int M, int N, int K)
{
  __shared__ u16 As[2][256 * 64];
  __shared__ u16 Bs[2][128 * 64];
  const int tid = threadIdx.x, lane = tid & 63, wid = tid >> 6;
  const int wm = wid >> 1, wn = wid & 1;
  const int row0 = blockIdx.y * 256, col0 = blockIdx.x * 128;
  const int NT = K >> 6;

  const int sr  = tid >> 3;
  const int scb = ((tid & 7) * 16) ^ ((sr & 7) << 4);

  auto stA = [&](int buf, int t, int u) {
    const u16* src = A + (size_t)(row0 + u * 64 + sr) * K + t * 64 + (scb >> 1);
    gload_lds16(src, As[buf] + u * 4096 + wid * 512);
  };
  auto stB = [&](int buf, int t, int u) {
    const u16* src = B + (size_t)(col0 + u * 64 + sr) * K + t * 64 + (scb >> 1);
    gload_lds16(src, Bs[buf] + u * 4096 + wid * 512);
  };
  auto ldA = [&](int buf, int mf, int k) {
    int ra = wm * 64 + mf * 16 + (lane & 15);
    int bc = (k * 64 + ((lane >> 4) << 4)) ^ ((ra & 7) << 4);
    return *(const bf16x8*)((const char*)As[buf] + ra * 128 + bc);
  };
  auto ldB = [&](int buf, int nf, int k) {
    int rb = wn * 64 + nf * 16 + (lane & 15);
    int bc = (k * 64 + ((lane >> 4) << 4)) ^ ((rb & 7) << 4);
    return *(const bf16x8*)((const char*)Bs[buf] + rb * 128 + bc);
  };

  f32x4 acc[4][4] = {};
  bf16x8 breg[4][2];

  stA(0, 0, 0); stA(0, 0, 1); stA(0, 0, 2); stA(0, 0, 3);
  stB(0, 0, 0); stB(0, 0, 1);
  stB(1, 1, 0); stB(1, 1, 1);
  asm volatile("s_waitcnt vmcnt(2)" ::: "memory");
  BAR();

  for (int it = 0; it < NT / 2; ++it) {
    const int t1  = 2 * it + 1;
    const int pf0 = (2 * it + 2 < NT) ? (2 * it + 2) : (NT - 1);
    const int pf1 = (2 * it + 3 < NT) ? (2 * it + 3) : (NT - 1);
    #pragma unroll
    for (int hf = 0; hf < 2; ++hf) {
      const int cb = hf;
      #pragma unroll
      for (int nf = 0; nf < 4; ++nf) { breg[nf][0] = ldB(cb, nf, 0); breg[nf][1] = ldB(cb, nf, 1); }
      bf16x8 a0 = ldA(cb, 0, 0), a1 = ldA(cb, 0, 1);
      BAR();
      if (hf == 0) { stA(1, t1, 0); stA(1, t1, 1); } else { stA(0, pf0, 0); stA(0, pf0, 1); }
      __builtin_amdgcn_s_setprio(1);
      #pragma unroll
      for (int nf = 0; nf < 4; ++nf) {
        acc[0][nf] = __builtin_amdgcn_mfma_f32_16x16x32_bf16(a0, breg[nf][0], acc[0][nf], 0, 0, 0);
        acc[0][nf] = __builtin_amdgcn_mfma_f32_16x16x32_bf16(a1, breg[nf][1], acc[0][nf], 0, 0, 0);
      }
      __builtin_amdgcn_s_setprio(0);
      bf16x8 b0 = ldA(cb, 1, 0), b1 = ldA(cb, 1, 1);
      bf16x8 c0 = ldA(cb, 2, 0), c1 = ldA(cb, 2, 1);
      BAR();
      if (hf == 0) { stA(1, t1, 2); stA(1, t1, 3); } else { stA(0, pf0, 2); stA(0, pf0, 3); }
      __builtin_amdgcn_s_setprio(1);
      #pragma unroll
      for (int nf = 0; nf < 4; ++nf) {
        acc[1][nf] = __builtin_amdgcn_mfma_f32_16x16x32_bf16(b0, breg[nf][0], acc[1][nf], 0, 0, 0);
        acc[1][nf] = __builtin_amdgcn_mfma_f32_16x16x32_bf16(b1, breg[nf][1], acc[1][nf], 0, 0, 0);
        acc[2][nf] = __builtin_amdgcn_mfma_f32_16x16x32_bf16(c0, breg[nf][0], acc[2][nf], 0, 0, 0);
        acc[2][nf] = __builtin_amdgcn_mfma_f32_16x16x32_bf16(c1, breg[nf][1], acc[2][nf], 0, 0, 0);
      }
      __builtin_amdgcn_s_setprio(0);
      a0 = ldA(cb, 3, 0); a1 = ldA(cb, 3, 1);
      BAR();
      if (hf == 0) { stB(0, pf0, 0); stB(0, pf0, 1); } else { stB(1, pf1, 0); stB(1, pf1, 1); }
      __builtin_amdgcn_s_setprio(1);
      #pragma unroll
      for (int nf = 0; nf < 4; ++nf) {
        acc[3][nf] = __builtin_amdgcn_mfma_f32_16x16x32_bf16(a0, breg[nf][0], acc[3][nf], 0, 0, 0);
        acc[3][nf] = __builtin_amdgcn_mfma_f32_16x16x32_bf16(a1, breg[nf][1], acc[3][nf], 0, 0, 0);
      }
      __builtin_amdgcn_s_setprio(0);
      asm volatile("s_waitcnt vmcnt(2)" ::: "memory");
      BAR();
    }
  }
  asm volatile("s_waitcnt vmcnt(0)" ::: "memory");

  #pragma unroll
  for (int mf = 0; mf < 4; ++mf) {
    #pragma unroll
    for (int nf = 0; nf < 4; ++nf) {
      #pragma unroll
      for (int e = 0; e < 4; ++e) {
        int r = row0 + wm * 64 + mf * 16 + (lane >> 4) * 4 + e;
        int c = col0 + wn * 64 + nf * 16 + (lane & 15);
        C[(size_t)r * N + c] = acc[mf][nf][e] + bias[c];
      }
    }
  }
}

// ---------------------------------------------------------------- attn staging helpers (QK stride 4096)
static __device__ __forceinline__ void stage_k_tile(
    const u16* __restrict__ QK, int b, int h, int j0, u16* Kbuf, int tid, int wid)
{
  #pragma unroll
  for (int i = 0; i < 4; i++) {
    int c = i * 256 + tid;
    int r = c >> 4, ob = (c & 15) * 16;
    int cb = ob ^ ((r & 7) << 4);
    const u16* g = QK + (size_t)(b*2048 + j0 + r) * 4096 + 2048 + h*128 + (cb >> 1);
    gload_lds16(g, Kbuf + (i * 256 + wid * 64) * 8);
  }
}
static __device__ __forceinline__ void stage_v_tile(
    const u16* __restrict__ Vt, int b, int h, int j0, u16* Vbuf, int tid, int wid)
{
  #pragma unroll
  for (int i = 0; i < 4; i++) {
    int c = i * 256 + tid;
    int r = c >> 3, ob = (c & 7) * 16;
    int cb = ob ^ ((r & 7) << 4);
    const u16* g = Vt + (size_t)((b*16 + h) * 128 + r) * 2048 + j0 + (cb >> 1);
    gload_lds16(g, Vbuf + (i * 256 + wid * 64) * 8);
  }
}

// ---------------------------------------------------------------- causal flash attention
__global__ __launch_bounds__(256) void attn(
    const u16* __restrict__ QK, const u16* __restrict__ Vt, u16* __restrict__ AO)
{
  const int flat = blockIdx.x + (blockIdx.y << 4) + (blockIdx.z << 8);
  const int swz = (flat & 7) * 64 + (flat >> 3);
  const int pair = swz & 15;
  const int h = (swz >> 4) & 15;
  const int b = swz >> 8;
  const int tid = threadIdx.x, lane = tid & 63, wid = tid >> 6;

  __shared__ u16 Ks[2][64 * 128];
  __shared__ u16 Vs[2][128 * 64];
  __shared__ u16 Ps[4][16 * 64];

  for (int side = 0; side < 2; side++) {
    const int pp = side ? (31 - pair) : pair;
    const int l0 = pp * 64;
    const int ntile = pp + 1;

    bf16x8 qa[4];
    const u16* qrow = QK + (size_t)(b*2048 + l0 + wid*16 + (lane & 15)) * 4096
                      + h*128 + (lane >> 4) * 8;
    #pragma unroll
    for (int ks = 0; ks < 4; ks++) qa[ks] = *(const bf16x8*)(qrow + ks * 32);

    f32x4 o[8] = {};
    float mrun[4] = {-1e30f, -1e30f, -1e30f, -1e30f};
    float lrun[4] = {};

    stage_v_tile(Vt, b, h, 0, Vs[0], tid, wid);
    stage_k_tile(QK, b, h, 0, Ks[0], tid, wid);
    int cur = 0;

    for (int t = 0; t < ntile; t++) {
      if (t + 1 < ntile) {
        stage_v_tile(Vt, b, h, (t + 1) * 64, Vs[cur ^ 1], tid, wid);
        stage_k_tile(QK, b, h, (t + 1) * 64, Ks[cur ^ 1], tid, wid);
        asm volatile("s_waitcnt vmcnt(8)" ::: "memory");
      } else {
        asm volatile("s_waitcnt vmcnt(0)" ::: "memory");
      }
      __builtin_amdgcn_s_barrier();
      asm volatile("" ::: "memory");

      f32x4 s[4] = {};
      const char* Kc = (const char*)Ks[cur];
      __builtin_amdgcn_s_setprio(1);
      #pragma unroll
      for (int nt = 0; nt < 4; nt++) {
        #pragma unroll
        for (int ks = 0; ks < 4; ks++) {
          int r = nt * 16 + (lane & 15);
          int cb = ks * 64 + (lane >> 4) * 16;
          bf16x8 kb = *(const bf16x8*)(Kc + r * 256 + (cb ^ ((lane & 7) << 4)));
          s[nt] = __builtin_amdgcn_mfma_f32_16x16x32_bf16(qa[ks], kb, s[nt], 0, 0, 0);
        }
      }
      __builtin_amdgcn_s_setprio(0);

      if (t == ntile - 1) {
        #pragma unroll
        for (int nt = 0; nt < 4; nt++) {
          #pragma unroll
          for (int e = 0; e < 4; e++) {
            int i_loc = wid * 16 + (lane >> 4) * 4 + e;
            int j_loc = nt * 16 + (lane & 15);
            if (j_loc > i_loc) s[nt][e] = -1e30f;
          }
        }
      }

      float pmax[4];
      #pragma unroll
      for (int e = 0; e < 4; e++) {
        float v = fmaxf(fmaxf(s[0][e], s[1][e]), fmaxf(s[2][e], s[3][e]));
        v = fmaxf(v, __shfl_xor(v, 1));
        v = fmaxf(v, __shfl_xor(v, 2));
        v = fmaxf(v, __shfl_xor(v, 4));
        v = fmaxf(v, __shfl_xor(v, 8));
        pmax[e] = v;
      }
      bool need = (pmax[0] > mrun[0] + 8.f) || (pmax[1] > mrun[1] + 8.f) ||
                  (pmax[2] > mrun[2] + 8.f) || (pmax[3] > mrun[3] + 8.f);
      if (__any(need)) {
        float alpha[4];
        #pragma unroll
        for (int e = 0; e < 4; e++) {
          float mi = fmaxf(mrun[e], pmax[e]);
          alpha[e] = exp2f(mrun[e] - mi);
          mrun[e] = mi;
          lrun[e] *= alpha[e];
        }
        #pragma unroll
        for (int dt = 0; dt < 8; dt++)
          #pragma unroll
          for (int e = 0; e < 4; e++)
            o[dt][e] *= alpha[e];
      }

      char* PsW = (char*)Ps[wid];
      #pragma unroll
      for (int nt = 0; nt < 4; nt++) {
        #pragma unroll
        for (int e = 0; e < 4; e++) {
          float p = exp2f(s[nt][e] - mrun[e]);
          lrun[e] += p;
          int i_ = (lane >> 4) * 4 + e;
          int jb = (nt * 16 + (lane & 15)) * 2;
          *(u16*)(PsW + i_ * 128 + (jb ^ ((i_ & 7) << 4))) = f2bf_trunc(p);
        }
      }

      const char* Vc = (const char*)Vs[cur];
      __builtin_amdgcn_s_setprio(1);
      #pragma unroll
      for (int ks = 0; ks < 2; ks++) {
        int ir = lane & 15;
        int jb = ks * 64 + (lane >> 4) * 16;
        bf16x8 pa = *(const bf16x8*)(PsW + ir * 128 + (jb ^ ((ir & 7) << 4)));
        #pragma unroll
        for (int dt = 0; dt < 8; dt++) {
          int dr = dt * 16 + (lane & 15);
          bf16x8 vb = *(const bf16x8*)(Vc + dr * 128 + (jb ^ ((lane & 7) << 4)));
          o[dt] = __builtin_amdgcn_mfma_f32_16x16x32_bf16(pa, vb, o[dt], 0, 0, 0);
        }
      }
      __builtin_amdgcn_s_setprio(0);

      asm volatile("s_waitcnt lgkmcnt(0)" ::: "memory");
      __builtin_amdgcn_s_barrier();
      asm volatile("" ::: "memory");
      cur ^= 1;
    }

    #pragma unroll
    for (int e = 0; e < 4; e++) {
      float l = lrun[e];
      l += __shfl_xor(l, 1);
      l += __shfl_xor(l, 2);
      l += __shfl_xor(l, 4);
      l += __shfl_xor(l, 8);
      float inv = 1.0f / l;
      int rglob = b * 2048 + l0 + wid * 16 + (lane >> 4) * 4 + e;
      #pragma unroll
      for (int dt = 0; dt < 8; dt++)
        AO[(size_t)rglob * 2048 + h * 128 + dt * 16 + (lane & 15)] = f2bf(o[dt][e] * inv);
    }
  }
}

// ---------------------------------------------------------------- launch
extern "C" void kernel_launch(void* const* d_in, const int* in_sizes, int n_in,
                              void* d_out, int out_size, void* d_ws, size_t ws_size,
                              hipStream_t stream)
{
  const float* x  = (const float*)d_in[0];
  const float* Wq = (const float*)d_in[1];
  const float* Wk = (const float*)d_in[2];
  const float* Wv = (const float*)d_in[3];
  const float* Wo = (const float*)d_in[4];
  const float* bo = (const float*)d_in[5];

  char* ws = (char*)d_ws;
  // [xb/AO 16MB][Wcat 24MB][Wob 8MB][QK 32MB][Vt 8MB] = 88 MB
  u16* xb   = (u16*)(ws);
  u16* Wcat = (u16*)(ws + 16777216);
  u16* Wob  = (u16*)(ws + 16777216 + 25165824);
  u16* QK   = (u16*)(ws + 16777216 + 25165824 + 8388608);
  u16* Vt   = (u16*)(ws + 16777216 + 25165824 + 8388608 + 33554432);
  u16* AO   = xb;

  cast_all<<<dim3(2048), dim3(256), 0, stream>>>(x, Wq, Wk, Wv, Wo, xb, Wcat, Wob);
  gemm_qkv<<<dim3(32, 24), dim3(512), 0, stream>>>(xb, Wcat, QK, Vt, 2048);
  attn<<<dim3(16, 16, 2), dim3(256), 0, stream>>>(QK, Vt, AO);
  gemm_ao<<<dim3(16, 16), dim3(512), 0, stream>>>(AO, Wob, (float*)d_out, bo, 4096, 2048, 2048);
}